// Round 17
// baseline (383.724 us; speedup 1.0000x reference)
//
#include <hip/hip_runtime.h>

#define HH 1024
#define VV 50257
#define ZS 50264    // padded z row stride
#define NPAD2 50432 // Wt rows = 788*64
#define NT 394      // big-gemm n-tiles (128 wide)
#define PLD 400
#define LL 64
#define BB 512
#define TRB 12608   // transpose blocks: 788 c-tiles * 16 k-tiles

typedef __bf16 bf16;
typedef bf16 bf16x8 __attribute__((ext_vector_type(8)));
typedef bf16 bf16x4v __attribute__((ext_vector_type(4)));
typedef float f32x4 __attribute__((ext_vector_type(4)));
typedef unsigned uint4v __attribute__((ext_vector_type(4)));

typedef __attribute__((address_space(1))) const unsigned int g_u32;
typedef __attribute__((address_space(3))) unsigned int l_u32;

static __device__ __forceinline__ bf16 f2bf(float f) {
  unsigned u = __builtin_bit_cast(unsigned, f);
  unsigned r = u + 0x7fffu + ((u >> 16) & 1u);
  unsigned short h = (unsigned short)(r >> 16);
  return __builtin_bit_cast(bf16, h);
}

static __device__ __forceinline__ unsigned cvt_pk(float lo, float hi) {
  unsigned r;
  asm("v_cvt_pk_bf16_f32 %0, %1, %2" : "=v"(r) : "v"(lo), "v"(hi));
  return r;
}

// ================= device pieces =================

// transpose+convert one 64x64 tile of out_W fp32[1024][50257] -> Wt bf16[50432][1024]
static __device__ void dev_tr(char* smemraw, int tb, const float* __restrict__ W,
                              bf16* __restrict__ Wt) {
  float(*T)[65] = (float(*)[65])smemraw;
  const int ct = tb % 788, kt = tb / 788;
  const int c0 = ct * 64, k0 = kt * 64;
  const int t = threadIdx.x;
  const int cc = t & 63, k4 = t >> 6;
  const int c = c0 + cc;
  if (c0 + 63 < VV) {
#pragma unroll
    for (int j = 0; j < 16; ++j)
      T[cc][k4 * 16 + j] = W[(size_t)(k0 + k4 * 16 + j) * VV + c];
  } else {
    const bool ok = c < VV;
#pragma unroll
    for (int j = 0; j < 16; ++j)
      T[cc][k4 * 16 + j] = ok ? W[(size_t)(k0 + k4 * 16 + j) * VV + c] : 0.f;
  }
  __syncthreads();
  const int cc2 = t >> 3, k8 = (t & 7) * 8;
#pragma unroll
  for (int r = 0; r < 2; ++r) {
    const int row = cc2 + 32 * r;
    float v[8];
#pragma unroll
    for (int e = 0; e < 8; ++e) v[e] = T[row][k8 + e];
    uint4v p = {cvt_pk(v[0], v[1]), cvt_pk(v[2], v[3]), cvt_pk(v[4], v[5]), cvt_pk(v[6], v[7])};
    *(uint4v*)(Wt + (size_t)(c0 + row) * HH + k0 + k8) = p;
  }
}

// generic small GEMM (R11-verified BK=32) + ldb for split-K BLAYOUT1.
// C(512 x N) = A(512 x Ktot bf16, lda) * B + bias; kb = bid/nwgx selects K-chunk of size K.
template <int BLAYOUT, int OMODE>
static __device__ void dev_gemm(char* smemraw, int bid, int nwgx,
                                const bf16* __restrict__ A, const float* __restrict__ Bm,
                                const float* __restrict__ bias, void* __restrict__ Cout,
                                int N, int K, int ldc, int lda, int ldb) {
  typedef unsigned short us40[64][40];
  us40* Bs = (us40*)smemraw;  // [2][64][40]
  const int t = threadIdx.x;
  const int kb = bid / nwgx;
  const int bidx = bid % nwgx;
  const int xcd = bidx & 7, jj = bidx >> 3;
  const int q = nwgx >> 3, r = nwgx & 7;
  const int w = (xcd < r ? xcd * (q + 1) : r * (q + 1) + (xcd - r) * q) + jj;
  const int n0 = (w >> 1) * 64;
  const int m0 = (w & 1) * 256;
  const int lane = t & 63, wv = t >> 6;
  const int lg = lane >> 4, lr = lane & 15;

  const bf16* Ap = A + (size_t)(m0 + wv * 64 + lr) * lda + (size_t)kb * K + lg * 8;

  const int sn0 = (BLAYOUT == 0) ? (t & 63) : (t >> 2);
  const int sk0 = (BLAYOUT == 0) ? ((t >> 6) * 8) : ((t & 3) * 8);

  auto stageB = [&](int buf, int k0) {
    if (BLAYOUT == 0) {
      const bool nok = (n0 + sn0) < N;
      const float* bsrc = Bm + (size_t)(kb * K + k0 + sk0) * N + n0 + sn0;
      float v[8];
#pragma unroll
      for (int e = 0; e < 8; ++e) v[e] = nok ? bsrc[(size_t)e * N] : 0.f;
      uint4v p = {cvt_pk(v[0], v[1]), cvt_pk(v[2], v[3]), cvt_pk(v[4], v[5]), cvt_pk(v[6], v[7])};
      *(uint4v*)(&Bs[buf][sn0][sk0]) = p;
    } else {
      const float* bsrc = Bm + (size_t)(n0 + sn0) * ldb + kb * K + k0 + sk0;
      float4 f0 = *(const float4*)(bsrc);
      float4 f1 = *(const float4*)(bsrc + 4);
      uint4v p = {cvt_pk(f0.x, f0.y), cvt_pk(f0.z, f0.w), cvt_pk(f1.x, f1.y), cvt_pk(f1.z, f1.w)};
      *(uint4v*)(&Bs[buf][sn0][sk0]) = p;
    }
  };

  f32x4 acc[4][4] = {};
  bf16x8 a[4], an[4];
#pragma unroll
  for (int i = 0; i < 4; ++i) a[i] = *(const bf16x8*)(Ap + (size_t)i * 16 * lda);

  const int nk = K >> 5;
  int cur = 0;
  stageB(0, 0);

  for (int ik = 0; ik < nk; ++ik) {
    __syncthreads();
    const bool more = (ik + 1 < nk);
    if (more) {
      stageB(cur ^ 1, (ik + 1) * 32);
#pragma unroll
      for (int i = 0; i < 4; ++i)
        an[i] = *(const bf16x8*)(Ap + (size_t)i * 16 * lda + (ik + 1) * 32);
    }
    bf16x8 b[4];
#pragma unroll
    for (int jx = 0; jx < 4; ++jx)
      b[jx] = *(const bf16x8*)(&Bs[cur][jx * 16 + lr][lg * 8]);
#pragma unroll
    for (int i = 0; i < 4; ++i)
#pragma unroll
      for (int jx = 0; jx < 4; ++jx)
        acc[i][jx] = __builtin_amdgcn_mfma_f32_16x16x32_bf16(a[i], b[jx], acc[i][jx], 0, 0, 0);
    if (more) {
#pragma unroll
      for (int i = 0; i < 4; ++i) a[i] = an[i];
    }
    cur ^= 1;
  }

  float bb[4];
#pragma unroll
  for (int jx = 0; jx < 4; ++jx) {
    int col = n0 + 16 * jx + lr;
    bb[jx] = (bias && col < N) ? bias[col] : 0.f;
  }
  float* co_f = (float*)Cout + (size_t)kb * BB * ldc;
  bf16* co_b = (bf16*)Cout;
#pragma unroll
  for (int i = 0; i < 4; ++i)
#pragma unroll
    for (int jx = 0; jx < 4; ++jx) {
      const int col = n0 + 16 * jx + lr;
      if (col < N) {
#pragma unroll
        for (int rr = 0; rr < 4; ++rr) {
          const int row = m0 + wv * 64 + 16 * i + lg * 4 + rr;
          float vvv = acc[i][jx][rr] + bb[jx];
          if (OMODE == 0)
            co_f[(size_t)row * ldc + col] = vvv;
          else if (OMODE == 1)
            co_b[(size_t)row * ldc + col] = f2bf(fmaxf(vvv, 0.f));
          else
            co_b[(size_t)row * ldc + col] = f2bf(vvv);
        }
      }
    }
}

// fused attention softmax + applied GEMM (R6/R8-verified)
static __device__ void dev_sapp(char* smemraw, int bid, const float* __restrict__ sp,
                                const float* __restrict__ attn_b, float* __restrict__ attn_out,
                                const float* __restrict__ enc, bf16* __restrict__ A_cat) {
  bf16(*aw)[72] = (bf16(*)[72])smemraw;                   // [256][72]
  bf16(*Bs)[72] = (bf16(*)[72])(smemraw + 256 * 72 * 2);  // [64][72]
  const int t = threadIdx.x;
  const int mhalf = bid & 1, nblk = bid >> 1;
  const int m0 = mhalf * 256, n0 = nblk * 64;
  const int lane = t & 63, wv = t >> 6;

#pragma unroll 4
  for (int rr = 0; rr < 64; ++rr) {
    const int row = m0 + wv * 64 + rr;
    const size_t idx = (size_t)row * LL + lane;
    float s = sp[idx] + sp[idx + (size_t)BB * LL] + sp[idx + (size_t)2 * BB * LL] +
              sp[idx + (size_t)3 * BB * LL] + attn_b[lane];
    float m = s;
#pragma unroll
    for (int off = 32; off; off >>= 1) m = fmaxf(m, __shfl_xor(m, off));
    float e = __expf(s - m);
    float sum = e;
#pragma unroll
    for (int off = 32; off; off >>= 1) sum += __shfl_xor(sum, off);
    float wvv = e / sum;
    if (nblk == 0) attn_out[idx] = wvv;
    aw[wv * 64 + rr][lane] = f2bf(wvv);
  }
  {
    const int n = t & 63, kb4 = (t >> 6) * 16;
#pragma unroll
    for (int kk = 0; kk < 16; ++kk)
      Bs[n][kb4 + kk] = f2bf(enc[(size_t)(kb4 + kk) * HH + n0 + n]);
  }
  __syncthreads();
  const int lg = lane >> 4, lr = lane & 15;
  f32x4 acc[4][4] = {};
#pragma unroll
  for (int kk = 0; kk < 2; ++kk) {
    bf16x8 a[4], b[4];
#pragma unroll
    for (int i = 0; i < 4; ++i)
      a[i] = *(const bf16x8*)(&aw[wv * 64 + 16 * i + lr][kk * 32 + lg * 8]);
#pragma unroll
    for (int j = 0; j < 4; ++j)
      b[j] = *(const bf16x8*)(&Bs[16 * j + lr][kk * 32 + lg * 8]);
#pragma unroll
    for (int i = 0; i < 4; ++i)
#pragma unroll
      for (int j = 0; j < 4; ++j)
        acc[i][j] = __builtin_amdgcn_mfma_f32_16x16x32_bf16(a[i], b[j], acc[i][j], 0, 0, 0);
  }
#pragma unroll
  for (int i = 0; i < 4; ++i)
#pragma unroll
    for (int j = 0; j < 4; ++j)
#pragma unroll
      for (int rr = 0; rr < 4; ++rr) {
        const int row = m0 + wv * 64 + 16 * i + lg * 4 + rr;
        A_cat[(size_t)row * 2048 + 1024 + n0 + 16 * j + lr] = f2bf(acc[i][j][rr]);
      }
}

static __device__ void dev_convert(int bid, const float* __restrict__ emb,
                                   const float* __restrict__ h0, bf16* __restrict__ A_cat,
                                   bf16* __restrict__ cat2) {
  int i = bid * 256 + threadIdx.x;
  int b = i >> 10, h = i & 1023;
  bf16 e = f2bf(emb[i]);
  A_cat[(size_t)b * 2048 + h] = e;
  cat2[(size_t)b * 2048 + h] = e;
  cat2[(size_t)b * 2048 + 1024 + h] = f2bf(h0[i]);
}

static __device__ void dev_smax(int bid, const float* __restrict__ sp,
                                const float* __restrict__ attn_b, float* __restrict__ attn_out,
                                bf16* __restrict__ aw_b) {
  const int t = threadIdx.x;
  const int row = bid * 4 + (t >> 6);
  const int l = t & 63;
  const size_t idx = (size_t)row * LL + l;
  float s = sp[idx] + sp[idx + (size_t)BB * LL] + sp[idx + (size_t)2 * BB * LL] +
            sp[idx + (size_t)3 * BB * LL] + attn_b[l];
  float m = s;
#pragma unroll
  for (int off = 32; off; off >>= 1) m = fmaxf(m, __shfl_xor(m, off));
  float e = __expf(s - m);
  float sum = e;
#pragma unroll
  for (int off = 32; off; off >>= 1) sum += __shfl_xor(sum, off);
  float wv = e / sum;
  attn_out[idx] = wv;
  aw_b[idx] = f2bf(wv);
}

// gru from split-K partials
static __device__ void dev_gru4(int bid, const float* __restrict__ gip,
                                const float* __restrict__ ghp, const float* __restrict__ b_ih,
                                const float* __restrict__ b_hh, const float* __restrict__ h0,
                                float* __restrict__ h1_out, bf16* __restrict__ h1b) {
  int i = bid * 256 + threadIdx.x;
  int b = i >> 10, h = i & 1023;
  size_t base = (size_t)b * 3072;
  const size_t PS = (size_t)BB * 3072;
  float ir = b_ih[h], iz = b_ih[1024 + h], in_ = b_ih[2048 + h];
  float hr = b_hh[h], hz = b_hh[1024 + h], hn = b_hh[2048 + h];
#pragma unroll
  for (int p = 0; p < 4; ++p) {
    ir += gip[p * PS + base + h];
    iz += gip[p * PS + base + 1024 + h];
    in_ += gip[p * PS + base + 2048 + h];
    hr += ghp[p * PS + base + h];
    hz += ghp[p * PS + base + 1024 + h];
    hn += ghp[p * PS + base + 2048 + h];
  }
  float r = 1.f / (1.f + __expf(-(ir + hr)));
  float z = 1.f / (1.f + __expf(-(iz + hz)));
  float n = tanhf(in_ + r * hn);
  float h1 = (1.f - z) * n + z * h0[i];
  h1_out[i] = h1;
  h1b[i] = f2bf(h1);
}

static __device__ void dev_gru(int bid, const float* __restrict__ gi, const float* __restrict__ gh,
                               const float* __restrict__ h0, float* __restrict__ h1_out,
                               bf16* __restrict__ h1b) {
  int i = bid * 256 + threadIdx.x;
  int b = i >> 10, h = i & 1023;
  size_t base = (size_t)b * 3072;
  float ir = gi[base + h], iz = gi[base + 1024 + h], in_ = gi[base + 2048 + h];
  float hr = gh[base + h], hz = gh[base + 1024 + h], hn = gh[base + 2048 + h];
  float r = 1.f / (1.f + __expf(-(ir + hr)));
  float z = 1.f / (1.f + __expf(-(iz + hz)));
  float n = tanhf(in_ + r * hn);
  float h1 = (1.f - z) * n + z * h0[i];
  h1_out[i] = h1;
  h1b[i] = f2bf(h1);
}

// x = relu(sum comb partials + comb_b) -> bf16
static __device__ void dev_xred(int bid, const float* __restrict__ cp,
                                const float* __restrict__ comb_b, bf16* __restrict__ x) {
  int i = bid * 256 + threadIdx.x;  // < 512*1024
  int col = i & 1023;
  const size_t PS = (size_t)BB * HH;
  float s = cp[i] + cp[PS + i] + cp[2 * PS + i] + cp[3 * PS + i] + comb_b[col];
  x[i] = f2bf(fmaxf(s, 0.f));
}

// ================= fast-path launches =================

// L1: fp32 scores (R9-verified) + convert + tr slice
__global__ __launch_bounds__(256) void k_head(const float* __restrict__ emb,
                                              const float* __restrict__ h0,
                                              const float* __restrict__ attn_W,
                                              float* __restrict__ sp, bf16* __restrict__ A_cat,
                                              bf16* __restrict__ cat2,
                                              const float* __restrict__ W, bf16* __restrict__ Wt,
                                              int trOff) {
  __shared__ __align__(16) char sm[16640];
  const int bid = blockIdx.x;
  if (bid < 512) {
    const int wv = threadIdx.x >> 6, lane = threadIdx.x & 63;
    const int rq = bid & 127, kc = bid >> 7;
    const int row = rq * 4 + wv;
    const float* Ar = (kc < 2) ? (emb + (size_t)row * HH + kc * 512)
                               : (h0 + (size_t)row * HH + (kc - 2) * 512);
    const float* Wb = attn_W + (size_t)(kc * 512) * LL + lane;
    float acc = 0.f;
#pragma unroll 4
    for (int k8 = 0; k8 < 64; ++k8) {
      float4 a0 = *(const float4*)(Ar + k8 * 8);
      float4 a1 = *(const float4*)(Ar + k8 * 8 + 4);
      const float* wp = Wb + (size_t)k8 * 8 * LL;
      acc = fmaf(a0.x, wp[0], acc);
      acc = fmaf(a0.y, wp[LL], acc);
      acc = fmaf(a0.z, wp[2 * LL], acc);
      acc = fmaf(a0.w, wp[3 * LL], acc);
      acc = fmaf(a1.x, wp[4 * LL], acc);
      acc = fmaf(a1.y, wp[5 * LL], acc);
      acc = fmaf(a1.z, wp[6 * LL], acc);
      acc = fmaf(a1.w, wp[7 * LL], acc);
    }
    sp[((size_t)kc * BB + row) * LL + lane] = acc;
  } else if (bid < 2560) {
    dev_convert(bid - 512, emb, h0, A_cat, cat2);
  } else {
    int tb = trOff + bid - 2560;
    if (tb < TRB) dev_tr(sm, tb, W, Wt);
  }
}

// L2: sapp (32) + gh split-K=4 (384) — no tr (46KB LDS)
__global__ __launch_bounds__(256) void k_sapp_gh(const float* sp, const float* attn_b,
                                                 float* attn_out, const float* enc, bf16* A_cat,
                                                 const bf16* cat2, const float* W_hh,
                                                 float* ghp) {
  __shared__ __align__(16) char sm[46080];
  const int bid = blockIdx.x;
  if (bid < 32) dev_sapp(sm, bid, sp, attn_b, attn_out, enc, A_cat);
  else dev_gemm<1, 0>(sm, bid - 32, 96, cat2 + 1024, W_hh, nullptr, ghp, 3 * HH, 256, 3 * HH,
                      2048, HH);
}

// L3: comb split-K=4 (128) + tr
__global__ __launch_bounds__(256, 3) void k_fat_comb4(const bf16* A_cat, const float* comb_W,
                                                      float* combp, const float* W, bf16* Wt,
                                                      int trOff) {
  __shared__ __align__(16) char sm[16640];
  const int bid = blockIdx.x;
  if (bid < 128)
    dev_gemm<0, 0>(sm, bid, 32, A_cat, comb_W, nullptr, combp, HH, 512, HH, 2048, 0);
  else { int tb = trOff + bid - 128; if (tb < TRB) dev_tr(sm, tb, W, Wt); }
}

// L4: x reduce (2048) + tr
__global__ __launch_bounds__(256) void k_fat_xred(const float* combp, const float* comb_b,
                                                  bf16* x, const float* W, bf16* Wt, int trOff) {
  __shared__ __align__(16) char sm[16640];
  const int bid = blockIdx.x;
  if (bid < 2048) dev_xred(bid, combp, comb_b, x);
  else { int tb = trOff + bid - 2048; if (tb < TRB) dev_tr(sm, tb, W, Wt); }
}

// L5: gi split-K=4 (384) + tr
__global__ __launch_bounds__(256, 3) void k_fat_gi4(const bf16* x, const float* W_ih, float* gip,
                                                    const float* W, bf16* Wt, int trOff) {
  __shared__ __align__(16) char sm[16640];
  const int bid = blockIdx.x;
  if (bid < 384)
    dev_gemm<1, 0>(sm, bid, 96, x, W_ih, nullptr, gip, 3 * HH, 256, 3 * HH, HH, HH);
  else { int tb = trOff + bid - 384; if (tb < TRB) dev_tr(sm, tb, W, Wt); }
}

// L6: gru from partials (2048) + tr
__global__ __launch_bounds__(256) void k_fat_gru4(const float* gip, const float* ghp,
                                                  const float* b_ih, const float* b_hh,
                                                  const float* h0, float* h1_out, bf16* h1b,
                                                  const float* W, bf16* Wt, int trOff) {
  __shared__ __align__(16) char sm[16640];
  const int bid = blockIdx.x;
  if (bid < 2048) dev_gru4(bid, gip, ghp, b_ih, b_hh, h0, h1_out, h1b);
  else { int tb = trOff + bid - 2048; if (tb < TRB) dev_tr(sm, tb, W, Wt); }
}

// ===== big GEMM: 256x128 tile, 8 waves; A direct-from-global (L2-resident, reg prefetch),
// B via global_load_lds NBUF=2; LDS 20KB -> 2 blocks/CU =====
__global__ __launch_bounds__(512, 4) void k_gemm_big(const bf16* __restrict__ A,
                                                     const bf16* __restrict__ Bt,
                                                     const float* __restrict__ bias,
                                                     bf16* __restrict__ C,
                                                     float* __restrict__ pm,
                                                     float* __restrict__ ps) {
  __shared__ __align__(16) bf16 Bsm[2][4096];  // 128r x 32k
  __shared__ float sm_m[2][256], sm_s[2][256];
  const int t = threadIdx.x;
  const int bid = blockIdx.x;
  const int nwg = gridDim.x;  // 788
  const int xcd = bid & 7, jj = bid >> 3;
  const int q = nwg >> 3, r = nwg & 7;
  const int w = (xcd < r ? xcd * (q + 1) : r * (q + 1) + (xcd - r) * q) + jj;
  const int m0 = (w & 1) * 256;  // m-innermost for B-panel L2 reuse
  const int n0 = (w >> 1) * 128;
  const int lane = t & 63, wv = t >> 6;
  const int wvm = wv >> 1, wvn = wv & 1;  // 4M x 2N
  const int lg = lane >> 4, lr = lane & 15;

  // B staging: wave wv stages rows wv*16..+15 (1 instr/thread)
  const int srow = lane >> 2;
  const int skk = (((lane & 3) ^ ((lane >> 3) & 3))) * 8;  // XOR-swizzled source granule
  const bf16* Bb0 = Bt + (size_t)(n0 + wv * 16 + srow) * HH + skk;

  auto stage = [&](int buf, int koff) {
    __builtin_amdgcn_global_load_lds((g_u32*)(Bb0 + koff), (l_u32*)(&Bsm[buf][wv * 512]), 16, 0, 0);
  };

  // A direct: fragment rows m0 + wvm*64 + 16*i + lr, k-offset lg*8 (bf16x8 = 16B/lane)
  const bf16* Ap = A + (size_t)(m0 + wvm * 64 + lr) * HH + lg * 8;

  f32x4 acc[4][4] = {};
  bf16x8 a[4], an[4];
#pragma unroll
  for (int i = 0; i < 4; ++i) a[i] = *(const bf16x8*)(Ap + (size_t)i * 16 * HH);

  stage(0, 0);
  __syncthreads();
  int cur = 0;
  const int nk = HH / 32;  // 32
  const int rga = (lr >> 1) & 3;  // read-side swizzle key
  for (int ik = 0; ik < nk; ++ik) {
    const bool more = (ik + 1 < nk);
    if (more) {
      stage(cur ^ 1, (ik + 1) * 32);
#pragma unroll
      for (int i = 0; i < 4; ++i)
        an[i] = *(const bf16x8*)(Ap + (size_t)i * 16 * HH + (ik + 1) * 32);
    }
    bf16x8 b[4];
#pragma unroll
    for (int j = 0; j < 4; ++j)
      b[j] = *(const bf16x8*)(&Bsm[cur][(wvn * 64 + 16 * j + lr) * 32 + ((lg ^ rga) * 8)]);
#pragma unroll
    for (int i = 0; i < 4; ++i)
#pragma unroll
      for (int j = 0; j < 4; ++j)
        acc[i][j] = __builtin_amdgcn_mfma_f32_16x16x32_bf16(a[i], b[j], acc[i][j], 0, 0, 0);
    if (more) {
#pragma unroll
      for (int i = 0; i < 4; ++i) a[i] = an[i];
    }
    __syncthreads();  // drains B prefetch + protects buffer swap
    cur ^= 1;
  }

  // fold bias
  float bb[4];
#pragma unroll
  for (int j = 0; j < 4; ++j) {
    const int col = n0 + wvn * 64 + 16 * j + lr;
    bb[j] = (col < VV) ? bias[col] : 0.f;
  }
#pragma unroll
  for (int i = 0; i < 4; ++i)
#pragma unroll
    for (int j = 0; j < 4; ++j)
#pragma unroll
      for (int rr = 0; rr < 4; ++rr) acc[i][j][rr] += bb[j];

  // store z
#pragma unroll
  for (int i = 0; i < 4; ++i)
#pragma unroll
    for (int j = 0; j < 4; ++j) {
      const int col = n0 + wvn * 64 + 16 * j + lr;
      if (col < VV) {
#pragma unroll
        for (int rr = 0; rr < 4; ++rr) {
          const int row = m0 + wvm * 64 + 16 * i + lg * 4 + rr;
          C[(size_t)row * ZS + col] = f2bf(acc[i][j][rr]);
        }
      }
    }

  // per-row (max,sumexp) partials over this block's 128 cols
#pragma unroll
  for (int i = 0; i < 4; ++i)
#pragma unroll
    for (int rr = 0; rr < 4; ++rr) {
      float mr = -1e30f;
#pragma unroll
      for (int j = 0; j < 4; ++j)
        if (n0 + wvn * 64 + 16 * j + lr < VV) mr = fmaxf(mr, acc[i][j][rr]);
      float sr = 0.f;
#pragma unroll
      for (int j = 0; j < 4; ++j)
        if (n0 + wvn * 64 + 16 * j + lr < VV) sr += __expf(acc[i][j][rr] - mr);
#pragma unroll
      for (int off = 1; off < 16; off <<= 1) {
        float mo = __shfl_xor(mr, off), so = __shfl_xor(sr, off);
        float nm = fmaxf(mr, mo);
        sr = sr * __expf(mr - nm) + so * __expf(mo - nm);
        mr = nm;
      }
      if (lr == 0) {
        const int row = wvm * 64 + 16 * i + lg * 4 + rr;
        sm_m[wvn][row] = mr;
        sm_s[wvn][row] = sr;
      }
    }
  __syncthreads();
  if (t < 256) {
    float M = sm_m[0][t], S = sm_s[0][t];
    float mo = sm_m[1][t], so = sm_s[1][t];
    float nm = fmaxf(M, mo);
    S = S * __expf(M - nm) + so * __expf(mo - nm);
    M = nm;
    const int grow = m0 + t;
    pm[(size_t)grow * PLD + (w >> 1)] = M;
    ps[(size_t)grow * PLD + (w >> 1)] = S;
  }
}

// ================= final subtract with fused per-row lse =================
__global__ __launch_bounds__(256) void k_out(const bf16* __restrict__ z,
                                             const float* __restrict__ pm,
                                             const float* __restrict__ ps,
                                             float* __restrict__ out) {
  const int b = blockIdx.y;
  const int t = threadIdx.x;
  __shared__ float lsev;
  if (t < 64) {
    float m = -1e30f, s = 0.f;
    for (int tt = t; tt < NT; tt += 64) {
      float mo = pm[(size_t)b * PLD + tt], so = ps[(size_t)b * PLD + tt];
      float nm = fmaxf(m, mo);
      s = s * __expf(m - nm) + so * __expf(mo - nm);
      m = nm;
    }
#pragma unroll
    for (int off = 32; off; off >>= 1) {
      float mo = __shfl_xor(m, off), so = __shfl_xor(s, off);
      float nm = fmaxf(m, mo);
      s = s * __expf(m - nm) + so * __expf(mo - nm);
      m = nm;
    }
    if (t == 0) lsev = logf(s) + m;
  }
  __syncthreads();
  const float l = lsev;
  const int c = (blockIdx.x * 256 + t) * 4;
  if (c >= VV) return;
  const bf16* zr = z + (size_t)b * ZS;
  float* orow = out + (size_t)b * VV;
  if (c + 4 <= VV) {
    bf16x4v v = *(const bf16x4v*)(zr + c);
    float4 o = make_float4((float)v[0] - l, (float)v[1] - l, (float)v[2] - l, (float)v[3] - l);
    *(float4*)(orow + c) = o;
  } else {
    for (int e = c; e < VV; ++e) orow[e] = (float)zr[e] - l;
  }
}

// ================= fallback (small ws): standalone kernels =================

template <int BLAYOUT, int OMODE>
__global__ __launch_bounds__(256, 3) void k_gemm(const bf16* A, const float* Bm, const float* bias,
                                                 void* Cout, int N, int K, int ldc, int lda,
                                                 int ldb) {
  __shared__ __align__(16) char sm[10240];
  dev_gemm<BLAYOUT, OMODE>(sm, blockIdx.y * gridDim.x + blockIdx.x, gridDim.x, A, Bm, bias, Cout,
                           N, K, ldc, lda, ldb);
}

__global__ __launch_bounds__(512) void k_lsm(const bf16* __restrict__ z, float* __restrict__ out) {
  const int b = blockIdx.x, t = threadIdx.x;
  const bf16* zr = z + (size_t)b * ZS;
  float m = -1e30f, s = 0.f;
  for (int c = t; c < 6282; c += 512) {
    bf16x8 v = *(const bf16x8*)(zr + (size_t)c * 8);
#pragma unroll
    for (int e = 0; e < 8; ++e) {
      float x = (float)v[e];
      float nm = fmaxf(m, x);
      s = s * __expf(m - nm) + __expf(x - nm);
      m = nm;
    }
  }
  if (t == 0) {
    float x = (float)zr[VV - 1];
    float nm = fmaxf(m, x);
    s = s * __expf(m - nm) + __expf(x - nm);
    m = nm;
  }
  for (int off = 32; off; off >>= 1) {
    float mo = __shfl_xor(m, off), so = __shfl_xor(s, off);
    float nm = fmaxf(m, mo);
    s = s * __expf(m - nm) + so * __expf(mo - nm);
    m = nm;
  }
  __shared__ float ms[8], ss[8];
  if ((t & 63) == 0) { ms[t >> 6] = m; ss[t >> 6] = s; }
  __syncthreads();
  if (t == 0) {
    float M = ms[0], S = ss[0];
    for (int wv = 1; wv < 8; ++wv) {
      float nm = fmaxf(M, ms[wv]);
      S = S * __expf(M - nm) + ss[wv] * __expf(ms[wv] - nm);
      M = nm;
    }
    ss[0] = logf(S) + M;
  }
  __syncthreads();
  const float lse = ss[0];
  float* orow = out + (size_t)b * VV;
  for (int v = t; v < VV; v += 512) orow[v] = (float)zr[v] - lse;
}

__global__ void k_convertG(const float* emb, const float* h0, bf16* A_cat, bf16* cat2) {
  dev_convert(blockIdx.x, emb, h0, A_cat, cat2);
}
__global__ void k_smaxG(const float* sp, const float* attn_b, float* attn_out, bf16* aw_b) {
  dev_smax(blockIdx.x, sp, attn_b, attn_out, aw_b);
}
__global__ void k_gruG(const float* gi, const float* gh, const float* h0, float* h1_out,
                       bf16* h1b) {
  dev_gru(blockIdx.x, gi, gh, h0, h1_out, h1b);
}

// ================= host =================

extern "C" void kernel_launch(void* const* d_in, const int* in_sizes, int n_in,
                              void* d_out, int out_size, void* d_ws, size_t ws_size,
                              hipStream_t stream) {
  const float* emb    = (const float*)d_in[0];
  const float* h0     = (const float*)d_in[1];
  const float* enc    = (const float*)d_in[2];
  const float* attn_W = (const float*)d_in[3];
  const float* attn_b = (const float*)d_in[4];
  const float* comb_W = (const float*)d_in[5];
  const float* comb_b = (const float*)d_in[6];
  const float* W_ih   = (const float*)d_in[7];
  const float* W_hh   = (const float*)d_in[8];
  const float* b_ih   = (const float*)d_in[9];
  const float* b_hh   = (const float*)d_in[10];
  const float* out_W  = (const float*)d_in[11];
  const float* out_b  = (const float*)d_in[12];

  float* out      = (float*)d_out;
  float* h1out    = out + (size_t)BB * VV;
  float* attn_out = h1out + (size_t)BB * HH;

  char* ws = (char*)d_ws;
  bf16* A_cat  = (bf16*)(ws);
  bf16* cat2   = (bf16*)(ws + 2097152);
  bf16* x      = (bf16*)(ws + 4194304);
  bf16* h1b    = (bf16*)(ws + 5242880);
  float* gi    = (float*)(ws + 6291456);             // fallback only
  float* gh    = (float*)(ws + 12582912);            // fallback only
  float* sp    = (float*)(ws + 18874368);
  bf16* aw_b   = (bf16*)(ws + 19398656);
  bf16* z      = (bf16*)(ws + 19464192);             // 512 x ZS bf16 (51.5 MB)
  bf16* Wt     = (bf16*)(ws + 70934528);             // 50432 x 1024 bf16 (103.3 MB)
  float* pm    = (float*)(ws + 174219264);           // 512 x 400 f32
  float* ps    = (float*)(ws + 175038464);           // 512 x 400 f32
  float* combp = (float*)(ws + 175857664);           // 4 x 512 x 1024 f32 (8.4 MB)
  float* ghp   = (float*)(ws + 184246272);           // 4 x 512 x 3072 f32 (25.2 MB)
  float* gip   = (float*)(ws + 209412096);           // 4 x 512 x 3072 f32 (25.2 MB)
  const size_t WS_NEED = 234577920ull;

  if (ws_size >= WS_NEED) {
    int off = 0;
    k_head<<<2560 + 3400, 256, 0, stream>>>(emb, h0, attn_W, sp, A_cat, cat2, out_W, Wt, off);
    off += 3400;
    k_sapp_gh<<<416, 256, 0, stream>>>(sp, attn_b, attn_out, enc, A_cat, cat2, W_hh, ghp);
    k_fat_comb4<<<128 + 2400, 256, 0, stream>>>(A_cat, comb_W, combp, out_W, Wt, off); off += 2400;
    k_fat_xred<<<2048 + 2200, 256, 0, stream>>>(combp, comb_b, x, out_W, Wt, off); off += 2200;
    k_fat_gi4<<<384 + 2400, 256, 0, stream>>>(x, W_ih, gip, out_W, Wt, off); off += 2400;
    k_fat_gru4<<<2048 + (TRB - off), 256, 0, stream>>>(gip, ghp, b_ih, b_hh, h0, h1out, h1b,
                                                       out_W, Wt, off);
    k_gemm_big<<<2 * NT, 512, 0, stream>>>(h1b, Wt, out_b, z, pm, ps);
    k_out<<<dim3(50, BB), 256, 0, stream>>>(z, pm, ps, out);
  } else {
    k_convertG<<<BB * HH / 256, 256, 0, stream>>>(emb, h0, A_cat, cat2);
    k_gemm<0, 0><<<dim3(2, 4), 256, 0, stream>>>(cat2, attn_W, nullptr, sp, LL, 512, LL, 2048, 0);
    k_smaxG<<<BB / 4, 256, 0, stream>>>(sp, attn_b, attn_out, aw_b);
    k_gemm<0, 2><<<dim3(32, 1), 256, 0, stream>>>(aw_b, enc, nullptr, A_cat + 1024, HH, LL, 2048, LL, 0);
    k_gemm<0, 1><<<dim3(32, 1), 256, 0, stream>>>(A_cat, comb_W, comb_b, x, HH, 2 * HH, HH, 2 * HH, 0);
    k_gemm<1, 0><<<dim3(96, 1), 256, 0, stream>>>(x, W_ih, b_ih, gi, 3 * HH, HH, 3 * HH, HH, HH);
    k_gemm<1, 0><<<dim3(96, 1), 256, 0, stream>>>(cat2 + 1024, W_hh, b_hh, gh, 3 * HH, HH, 3 * HH, 2048, HH);
    k_gruG<<<BB * HH / 256, 256, 0, stream>>>(gi, gh, h0, h1out, h1b);
    k_gemm<0, 2><<<dim3(2 * ((VV + 63) / 64), 1), 256, 0, stream>>>(h1b, out_W, out_b, z, VV, HH, ZS, HH, 0);
    k_lsm<<<BB, 512, 0, stream>>>(z, out);
  }
}

// Round 19
// 338.725 us; speedup vs baseline: 1.1328x; 1.1328x over previous
//
#include <hip/hip_runtime.h>

#define HH 1024
#define VV 50257
#define ZS 50264    // padded z row stride
#define NPAD2 50432 // Wt rows = 788*64
#define NT 394      // big-gemm n-tiles (128 wide)
#define PLD 400
#define LL 64
#define BB 512
#define TRB 12608   // transpose blocks: 788 c-tiles * 16 k-tiles
#define SK 8        // split-K ways for chain GEMMs

typedef __bf16 bf16;
typedef bf16 bf16x8 __attribute__((ext_vector_type(8)));
typedef bf16 bf16x4v __attribute__((ext_vector_type(4)));
typedef float f32x4 __attribute__((ext_vector_type(4)));
typedef unsigned uint4v __attribute__((ext_vector_type(4)));

typedef __attribute__((address_space(1))) const unsigned int g_u32;
typedef __attribute__((address_space(3))) unsigned int l_u32;

static __device__ __forceinline__ bf16 f2bf(float f) {
  unsigned u = __builtin_bit_cast(unsigned, f);
  unsigned r = u + 0x7fffu + ((u >> 16) & 1u);
  unsigned short h = (unsigned short)(r >> 16);
  return __builtin_bit_cast(bf16, h);
}

static __device__ __forceinline__ unsigned cvt_pk(float lo, float hi) {
  unsigned r;
  asm("v_cvt_pk_bf16_f32 %0, %1, %2" : "=v"(r) : "v"(lo), "v"(hi));
  return r;
}

// ================= device pieces =================

// transpose+convert one 64x64 tile of out_W fp32[1024][50257] -> Wt bf16[50432][1024]
static __device__ void dev_tr(char* smemraw, int tb, const float* __restrict__ W,
                              bf16* __restrict__ Wt) {
  float(*T)[65] = (float(*)[65])smemraw;
  const int ct = tb % 788, kt = tb / 788;
  const int c0 = ct * 64, k0 = kt * 64;
  const int t = threadIdx.x;
  const int cc = t & 63, k4 = t >> 6;
  const int c = c0 + cc;
  if (c0 + 63 < VV) {
#pragma unroll
    for (int j = 0; j < 16; ++j)
      T[cc][k4 * 16 + j] = W[(size_t)(k0 + k4 * 16 + j) * VV + c];
  } else {
    const bool ok = c < VV;
#pragma unroll
    for (int j = 0; j < 16; ++j)
      T[cc][k4 * 16 + j] = ok ? W[(size_t)(k0 + k4 * 16 + j) * VV + c] : 0.f;
  }
  __syncthreads();
  const int cc2 = t >> 3, k8 = (t & 7) * 8;
#pragma unroll
  for (int r = 0; r < 2; ++r) {
    const int row = cc2 + 32 * r;
    float v[8];
#pragma unroll
    for (int e = 0; e < 8; ++e) v[e] = T[row][k8 + e];
    uint4v p = {cvt_pk(v[0], v[1]), cvt_pk(v[2], v[3]), cvt_pk(v[4], v[5]), cvt_pk(v[6], v[7])};
    *(uint4v*)(Wt + (size_t)(c0 + row) * HH + k0 + k8) = p;
  }
}

// generic small GEMM (R11-verified BK=32) + ldb for split-K BLAYOUT1.
// C(512 x N) = A(512 x Ktot bf16, lda) * B + bias; kb = bid/nwgx selects K-chunk of size K.
template <int BLAYOUT, int OMODE>
static __device__ void dev_gemm(char* smemraw, int bid, int nwgx,
                                const bf16* __restrict__ A, const float* __restrict__ Bm,
                                const float* __restrict__ bias, void* __restrict__ Cout,
                                int N, int K, int ldc, int lda, int ldb) {
  typedef unsigned short us40[64][40];
  us40* Bs = (us40*)smemraw;  // [2][64][40]
  const int t = threadIdx.x;
  const int kb = bid / nwgx;
  const int bidx = bid % nwgx;
  const int xcd = bidx & 7, jj = bidx >> 3;
  const int q = nwgx >> 3, r = nwgx & 7;
  const int w = (xcd < r ? xcd * (q + 1) : r * (q + 1) + (xcd - r) * q) + jj;
  const int n0 = (w >> 1) * 64;
  const int m0 = (w & 1) * 256;
  const int lane = t & 63, wv = t >> 6;
  const int lg = lane >> 4, lr = lane & 15;

  const bf16* Ap = A + (size_t)(m0 + wv * 64 + lr) * lda + (size_t)kb * K + lg * 8;

  const int sn0 = (BLAYOUT == 0) ? (t & 63) : (t >> 2);
  const int sk0 = (BLAYOUT == 0) ? ((t >> 6) * 8) : ((t & 3) * 8);

  auto stageB = [&](int buf, int k0) {
    if (BLAYOUT == 0) {
      const bool nok = (n0 + sn0) < N;
      const float* bsrc = Bm + (size_t)(kb * K + k0 + sk0) * N + n0 + sn0;
      float v[8];
#pragma unroll
      for (int e = 0; e < 8; ++e) v[e] = nok ? bsrc[(size_t)e * N] : 0.f;
      uint4v p = {cvt_pk(v[0], v[1]), cvt_pk(v[2], v[3]), cvt_pk(v[4], v[5]), cvt_pk(v[6], v[7])};
      *(uint4v*)(&Bs[buf][sn0][sk0]) = p;
    } else {
      const float* bsrc = Bm + (size_t)(n0 + sn0) * ldb + kb * K + k0 + sk0;
      float4 f0 = *(const float4*)(bsrc);
      float4 f1 = *(const float4*)(bsrc + 4);
      uint4v p = {cvt_pk(f0.x, f0.y), cvt_pk(f0.z, f0.w), cvt_pk(f1.x, f1.y), cvt_pk(f1.z, f1.w)};
      *(uint4v*)(&Bs[buf][sn0][sk0]) = p;
    }
  };

  f32x4 acc[4][4] = {};
  bf16x8 a[4], an[4];
#pragma unroll
  for (int i = 0; i < 4; ++i) a[i] = *(const bf16x8*)(Ap + (size_t)i * 16 * lda);

  const int nk = K >> 5;
  int cur = 0;
  stageB(0, 0);

  for (int ik = 0; ik < nk; ++ik) {
    __syncthreads();
    const bool more = (ik + 1 < nk);
    if (more) {
      stageB(cur ^ 1, (ik + 1) * 32);
#pragma unroll
      for (int i = 0; i < 4; ++i)
        an[i] = *(const bf16x8*)(Ap + (size_t)i * 16 * lda + (ik + 1) * 32);
    }
    bf16x8 b[4];
#pragma unroll
    for (int jx = 0; jx < 4; ++jx)
      b[jx] = *(const bf16x8*)(&Bs[cur][jx * 16 + lr][lg * 8]);
#pragma unroll
    for (int i = 0; i < 4; ++i)
#pragma unroll
      for (int jx = 0; jx < 4; ++jx)
        acc[i][jx] = __builtin_amdgcn_mfma_f32_16x16x32_bf16(a[i], b[jx], acc[i][jx], 0, 0, 0);
    if (more) {
#pragma unroll
      for (int i = 0; i < 4; ++i) a[i] = an[i];
    }
    cur ^= 1;
  }

  float bb[4];
#pragma unroll
  for (int jx = 0; jx < 4; ++jx) {
    int col = n0 + 16 * jx + lr;
    bb[jx] = (bias && col < N) ? bias[col] : 0.f;
  }
  float* co_f = (float*)Cout + (size_t)kb * BB * ldc;
  bf16* co_b = (bf16*)Cout;
#pragma unroll
  for (int i = 0; i < 4; ++i)
#pragma unroll
    for (int jx = 0; jx < 4; ++jx) {
      const int col = n0 + 16 * jx + lr;
      if (col < N) {
#pragma unroll
        for (int rr = 0; rr < 4; ++rr) {
          const int row = m0 + wv * 64 + 16 * i + lg * 4 + rr;
          float vvv = acc[i][jx][rr] + bb[jx];
          if (OMODE == 0)
            co_f[(size_t)row * ldc + col] = vvv;
          else if (OMODE == 1)
            co_b[(size_t)row * ldc + col] = f2bf(fmaxf(vvv, 0.f));
          else
            co_b[(size_t)row * ldc + col] = f2bf(vvv);
        }
      }
    }
}

// fused attention softmax + applied GEMM (R6/R8-verified)
static __device__ void dev_sapp(char* smemraw, int bid, const float* __restrict__ sp,
                                const float* __restrict__ attn_b, float* __restrict__ attn_out,
                                const float* __restrict__ enc, bf16* __restrict__ A_cat) {
  bf16(*aw)[72] = (bf16(*)[72])smemraw;                   // [256][72]
  bf16(*Bs)[72] = (bf16(*)[72])(smemraw + 256 * 72 * 2);  // [64][72]
  const int t = threadIdx.x;
  const int mhalf = bid & 1, nblk = bid >> 1;
  const int m0 = mhalf * 256, n0 = nblk * 64;
  const int lane = t & 63, wv = t >> 6;

#pragma unroll 4
  for (int rr = 0; rr < 64; ++rr) {
    const int row = m0 + wv * 64 + rr;
    const size_t idx = (size_t)row * LL + lane;
    float s = sp[idx] + sp[idx + (size_t)BB * LL] + sp[idx + (size_t)2 * BB * LL] +
              sp[idx + (size_t)3 * BB * LL] + attn_b[lane];
    float m = s;
#pragma unroll
    for (int off = 32; off; off >>= 1) m = fmaxf(m, __shfl_xor(m, off));
    float e = __expf(s - m);
    float sum = e;
#pragma unroll
    for (int off = 32; off; off >>= 1) sum += __shfl_xor(sum, off);
    float wvv = e / sum;
    if (nblk == 0) attn_out[idx] = wvv;
    aw[wv * 64 + rr][lane] = f2bf(wvv);
  }
  {
    const int n = t & 63, kb4 = (t >> 6) * 16;
#pragma unroll
    for (int kk = 0; kk < 16; ++kk)
      Bs[n][kb4 + kk] = f2bf(enc[(size_t)(kb4 + kk) * HH + n0 + n]);
  }
  __syncthreads();
  const int lg = lane >> 4, lr = lane & 15;
  f32x4 acc[4][4] = {};
#pragma unroll
  for (int kk = 0; kk < 2; ++kk) {
    bf16x8 a[4], b[4];
#pragma unroll
    for (int i = 0; i < 4; ++i)
      a[i] = *(const bf16x8*)(&aw[wv * 64 + 16 * i + lr][kk * 32 + lg * 8]);
#pragma unroll
    for (int j = 0; j < 4; ++j)
      b[j] = *(const bf16x8*)(&Bs[16 * j + lr][kk * 32 + lg * 8]);
#pragma unroll
    for (int i = 0; i < 4; ++i)
#pragma unroll
      for (int j = 0; j < 4; ++j)
        acc[i][j] = __builtin_amdgcn_mfma_f32_16x16x32_bf16(a[i], b[j], acc[i][j], 0, 0, 0);
  }
#pragma unroll
  for (int i = 0; i < 4; ++i)
#pragma unroll
    for (int j = 0; j < 4; ++j)
#pragma unroll
      for (int rr = 0; rr < 4; ++rr) {
        const int row = m0 + wv * 64 + 16 * i + lg * 4 + rr;
        A_cat[(size_t)row * 2048 + 1024 + n0 + 16 * j + lr] = f2bf(acc[i][j][rr]);
      }
}

static __device__ void dev_convert(int bid, const float* __restrict__ emb,
                                   const float* __restrict__ h0, bf16* __restrict__ A_cat,
                                   bf16* __restrict__ cat2) {
  int i = bid * 256 + threadIdx.x;
  int b = i >> 10, h = i & 1023;
  bf16 e = f2bf(emb[i]);
  A_cat[(size_t)b * 2048 + h] = e;
  cat2[(size_t)b * 2048 + h] = e;
  cat2[(size_t)b * 2048 + 1024 + h] = f2bf(h0[i]);
}

static __device__ void dev_smax(int bid, const float* __restrict__ sp,
                                const float* __restrict__ attn_b, float* __restrict__ attn_out,
                                bf16* __restrict__ aw_b) {
  const int t = threadIdx.x;
  const int row = bid * 4 + (t >> 6);
  const int l = t & 63;
  const size_t idx = (size_t)row * LL + l;
  float s = sp[idx] + sp[idx + (size_t)BB * LL] + sp[idx + (size_t)2 * BB * LL] +
            sp[idx + (size_t)3 * BB * LL] + attn_b[l];
  float m = s;
#pragma unroll
  for (int off = 32; off; off >>= 1) m = fmaxf(m, __shfl_xor(m, off));
  float e = __expf(s - m);
  float sum = e;
#pragma unroll
  for (int off = 32; off; off >>= 1) sum += __shfl_xor(sum, off);
  float wv = e / sum;
  attn_out[idx] = wv;
  aw_b[idx] = f2bf(wv);
}

// gru from SK split-K partials
static __device__ void dev_gru8(int bid, const float* __restrict__ gip,
                                const float* __restrict__ ghp, const float* __restrict__ b_ih,
                                const float* __restrict__ b_hh, const float* __restrict__ h0,
                                float* __restrict__ h1_out, bf16* __restrict__ h1b) {
  int i = bid * 256 + threadIdx.x;
  int b = i >> 10, h = i & 1023;
  size_t base = (size_t)b * 3072;
  const size_t PS = (size_t)BB * 3072;
  float ir = b_ih[h], iz = b_ih[1024 + h], in_ = b_ih[2048 + h];
  float hr = b_hh[h], hz = b_hh[1024 + h], hn = b_hh[2048 + h];
#pragma unroll
  for (int p = 0; p < SK; ++p) {
    ir += gip[p * PS + base + h];
    iz += gip[p * PS + base + 1024 + h];
    in_ += gip[p * PS + base + 2048 + h];
    hr += ghp[p * PS + base + h];
    hz += ghp[p * PS + base + 1024 + h];
    hn += ghp[p * PS + base + 2048 + h];
  }
  float r = 1.f / (1.f + __expf(-(ir + hr)));
  float z = 1.f / (1.f + __expf(-(iz + hz)));
  float n = tanhf(in_ + r * hn);
  float h1 = (1.f - z) * n + z * h0[i];
  h1_out[i] = h1;
  h1b[i] = f2bf(h1);
}

static __device__ void dev_gru(int bid, const float* __restrict__ gi, const float* __restrict__ gh,
                               const float* __restrict__ h0, float* __restrict__ h1_out,
                               bf16* __restrict__ h1b) {
  int i = bid * 256 + threadIdx.x;
  int b = i >> 10, h = i & 1023;
  size_t base = (size_t)b * 3072;
  float ir = gi[base + h], iz = gi[base + 1024 + h], in_ = gi[base + 2048 + h];
  float hr = gh[base + h], hz = gh[base + 1024 + h], hn = gh[base + 2048 + h];
  float r = 1.f / (1.f + __expf(-(ir + hr)));
  float z = 1.f / (1.f + __expf(-(iz + hz)));
  float n = tanhf(in_ + r * hn);
  float h1 = (1.f - z) * n + z * h0[i];
  h1_out[i] = h1;
  h1b[i] = f2bf(h1);
}

// x = relu(sum SK comb partials + comb_b) -> bf16
static __device__ void dev_xred(int bid, const float* __restrict__ cp,
                                const float* __restrict__ comb_b, bf16* __restrict__ x) {
  int i = bid * 256 + threadIdx.x;  // < 512*1024
  int col = i & 1023;
  const size_t PS = (size_t)BB * HH;
  float s = comb_b[col];
#pragma unroll
  for (int p = 0; p < SK; ++p) s += cp[p * PS + i];
  x[i] = f2bf(fmaxf(s, 0.f));
}

// ================= fast-path launches =================

// L1: fp32 scores (512) + convert (2048) + tr slice (3400)
__global__ __launch_bounds__(256) void k_head(const float* __restrict__ emb,
                                              const float* __restrict__ h0,
                                              const float* __restrict__ attn_W,
                                              float* __restrict__ sp, bf16* __restrict__ A_cat,
                                              bf16* __restrict__ cat2,
                                              const float* __restrict__ W, bf16* __restrict__ Wt,
                                              int trOff) {
  __shared__ __align__(16) char sm[16640];
  const int bid = blockIdx.x;
  if (bid < 512) {
    const int wv = threadIdx.x >> 6, lane = threadIdx.x & 63;
    const int rq = bid & 127, kc = bid >> 7;
    const int row = rq * 4 + wv;
    const float* Ar = (kc < 2) ? (emb + (size_t)row * HH + kc * 512)
                               : (h0 + (size_t)row * HH + (kc - 2) * 512);
    const float* Wb = attn_W + (size_t)(kc * 512) * LL + lane;
    float acc = 0.f;
#pragma unroll 4
    for (int k8 = 0; k8 < 64; ++k8) {
      float4 a0 = *(const float4*)(Ar + k8 * 8);
      float4 a1 = *(const float4*)(Ar + k8 * 8 + 4);
      const float* wp = Wb + (size_t)k8 * 8 * LL;
      acc = fmaf(a0.x, wp[0], acc);
      acc = fmaf(a0.y, wp[LL], acc);
      acc = fmaf(a0.z, wp[2 * LL], acc);
      acc = fmaf(a0.w, wp[3 * LL], acc);
      acc = fmaf(a1.x, wp[4 * LL], acc);
      acc = fmaf(a1.y, wp[5 * LL], acc);
      acc = fmaf(a1.z, wp[6 * LL], acc);
      acc = fmaf(a1.w, wp[7 * LL], acc);
    }
    sp[((size_t)kc * BB + row) * LL + lane] = acc;
  } else if (bid < 2560) {
    dev_convert(bid - 512, emb, h0, A_cat, cat2);
  } else {
    int tb = trOff + bid - 2560;
    if (tb < TRB) dev_tr(sm, tb, W, Wt);
  }
}

// L2: sapp (32) + gh split-K=8 (768)
__global__ __launch_bounds__(256) void k_sapp_gh(const float* sp, const float* attn_b,
                                                 float* attn_out, const float* enc, bf16* A_cat,
                                                 const bf16* cat2, const float* W_hh,
                                                 float* ghp) {
  __shared__ __align__(16) char sm[46080];
  const int bid = blockIdx.x;
  if (bid < 32) dev_sapp(sm, bid, sp, attn_b, attn_out, enc, A_cat);
  else dev_gemm<1, 0>(sm, bid - 32, 96, cat2 + 1024, W_hh, nullptr, ghp, 3 * HH, HH / SK,
                      3 * HH, 2048, HH);
}

// L3: comb split-K=8 (256) + tr
__global__ __launch_bounds__(256, 3) void k_fat_comb8(const bf16* A_cat, const float* comb_W,
                                                      float* combp, const float* W, bf16* Wt,
                                                      int trOff) {
  __shared__ __align__(16) char sm[16640];
  const int bid = blockIdx.x;
  if (bid < 32 * SK)
    dev_gemm<0, 0>(sm, bid, 32, A_cat, comb_W, nullptr, combp, HH, 2 * HH / SK, HH, 2048, 0);
  else { int tb = trOff + bid - 32 * SK; if (tb < TRB) dev_tr(sm, tb, W, Wt); }
}

// L4: x reduce (2048) + tr
__global__ __launch_bounds__(256) void k_fat_xred(const float* combp, const float* comb_b,
                                                  bf16* x, const float* W, bf16* Wt, int trOff) {
  __shared__ __align__(16) char sm[16640];
  const int bid = blockIdx.x;
  if (bid < 2048) dev_xred(bid, combp, comb_b, x);
  else { int tb = trOff + bid - 2048; if (tb < TRB) dev_tr(sm, tb, W, Wt); }
}

// L5: gi split-K=8 (768) + tr
__global__ __launch_bounds__(256, 3) void k_fat_gi8(const bf16* x, const float* W_ih, float* gip,
                                                    const float* W, bf16* Wt, int trOff) {
  __shared__ __align__(16) char sm[16640];
  const int bid = blockIdx.x;
  if (bid < 96 * SK)
    dev_gemm<1, 0>(sm, bid, 96, x, W_ih, nullptr, gip, 3 * HH, HH / SK, 3 * HH, HH, HH);
  else { int tb = trOff + bid - 96 * SK; if (tb < TRB) dev_tr(sm, tb, W, Wt); }
}

// L6: gru from partials (2048) + tr
__global__ __launch_bounds__(256) void k_fat_gru8(const float* gip, const float* ghp,
                                                  const float* b_ih, const float* b_hh,
                                                  const float* h0, float* h1_out, bf16* h1b,
                                                  const float* W, bf16* Wt, int trOff) {
  __shared__ __align__(16) char sm[16640];
  const int bid = blockIdx.x;
  if (bid < 2048) dev_gru8(bid, gip, ghp, b_ih, b_hh, h0, h1_out, h1b);
  else { int tb = trOff + bid - 2048; if (tb < TRB) dev_tr(sm, tb, W, Wt); }
}

// ===== big GEMM (R11/R16-verified): 256x128 tile, 8 waves, NBUF=2, 2 blocks/CU =====
__global__ __launch_bounds__(512, 4) void k_gemm_big(const bf16* __restrict__ A,
                                                     const bf16* __restrict__ Bt,
                                                     const float* __restrict__ bias,
                                                     bf16* __restrict__ C,
                                                     float* __restrict__ pm,
                                                     float* __restrict__ ps) {
  __shared__ __align__(16) bf16 Asm[2][8192];
  __shared__ __align__(16) bf16 Bsm[2][4096];
  __shared__ float sm_m[2][256], sm_s[2][256];
  const int t = threadIdx.x;
  const int bid = blockIdx.x;
  const int nwg = gridDim.x;  // 788
  const int xcd = bid & 7, jj = bid >> 3;
  const int q = nwg >> 3, r = nwg & 7;
  const int w = (xcd < r ? xcd * (q + 1) : r * (q + 1) + (xcd - r) * q) + jj;
  const int m0 = (w & 1) * 256;
  const int n0 = (w >> 1) * 128;
  const int lane = t & 63, wv = t >> 6;
  const int wvm = wv >> 1, wvn = wv & 1;
  const int lg = lane >> 4, lr = lane & 15;

  const int srow = lane >> 2;
  const int skk = (((lane & 3) ^ ((lane >> 3) & 3))) * 8;
  const bf16* Aa0 = A + (size_t)(m0 + wv * 32 + srow) * HH + skk;
  const bf16* Aa1 = Aa0 + (size_t)16 * HH;
  const bf16* Bb0 = Bt + (size_t)(n0 + wv * 16 + srow) * HH + skk;

  auto stage = [&](int buf, int koff) {
    __builtin_amdgcn_global_load_lds((g_u32*)(Aa0 + koff), (l_u32*)(&Asm[buf][wv * 1024]), 16, 0, 0);
    __builtin_amdgcn_global_load_lds((g_u32*)(Aa1 + koff), (l_u32*)(&Asm[buf][wv * 1024 + 512]), 16, 0, 0);
    __builtin_amdgcn_global_load_lds((g_u32*)(Bb0 + koff), (l_u32*)(&Bsm[buf][wv * 512]), 16, 0, 0);
  };

  f32x4 acc[4][4] = {};
  stage(0, 0);
  __syncthreads();
  int cur = 0;
  const int nk = HH / 32;
  const int rga = (lr >> 1) & 3;
  for (int ik = 0; ik < nk; ++ik) {
    if (ik + 1 < nk) stage(cur ^ 1, (ik + 1) * 32);
    bf16x8 a[4], b[4];
#pragma unroll
    for (int i = 0; i < 4; ++i)
      a[i] = *(const bf16x8*)(&Asm[cur][(wvm * 64 + 16 * i + lr) * 32 + ((lg ^ rga) * 8)]);
#pragma unroll
    for (int j = 0; j < 4; ++j)
      b[j] = *(const bf16x8*)(&Bsm[cur][(wvn * 64 + 16 * j + lr) * 32 + ((lg ^ rga) * 8)]);
#pragma unroll
    for (int i = 0; i < 4; ++i)
#pragma unroll
      for (int j = 0; j < 4; ++j)
        acc[i][j] = __builtin_amdgcn_mfma_f32_16x16x32_bf16(a[i], b[j], acc[i][j], 0, 0, 0);
    __syncthreads();
    cur ^= 1;
  }

  float bb[4];
#pragma unroll
  for (int j = 0; j < 4; ++j) {
    const int col = n0 + wvn * 64 + 16 * j + lr;
    bb[j] = (col < VV) ? bias[col] : 0.f;
  }
#pragma unroll
  for (int i = 0; i < 4; ++i)
#pragma unroll
    for (int j = 0; j < 4; ++j)
#pragma unroll
      for (int rr = 0; rr < 4; ++rr) acc[i][j][rr] += bb[j];

#pragma unroll
  for (int i = 0; i < 4; ++i)
#pragma unroll
    for (int j = 0; j < 4; ++j) {
      const int col = n0 + wvn * 64 + 16 * j + lr;
      if (col < VV) {
#pragma unroll
        for (int rr = 0; rr < 4; ++rr) {
          const int row = m0 + wvm * 64 + 16 * i + lg * 4 + rr;
          C[(size_t)row * ZS + col] = f2bf(acc[i][j][rr]);
        }
      }
    }

#pragma unroll
  for (int i = 0; i < 4; ++i)
#pragma unroll
    for (int rr = 0; rr < 4; ++rr) {
      float mr = -1e30f;
#pragma unroll
      for (int j = 0; j < 4; ++j)
        if (n0 + wvn * 64 + 16 * j + lr < VV) mr = fmaxf(mr, acc[i][j][rr]);
      float sr = 0.f;
#pragma unroll
      for (int j = 0; j < 4; ++j)
        if (n0 + wvn * 64 + 16 * j + lr < VV) sr += __expf(acc[i][j][rr] - mr);
#pragma unroll
      for (int off = 1; off < 16; off <<= 1) {
        float mo = __shfl_xor(mr, off), so = __shfl_xor(sr, off);
        float nm = fmaxf(mr, mo);
        sr = sr * __expf(mr - nm) + so * __expf(mo - nm);
        mr = nm;
      }
      if (lr == 0) {
        const int row = wvm * 64 + 16 * i + lg * 4 + rr;
        sm_m[wvn][row] = mr;
        sm_s[wvn][row] = sr;
      }
    }
  __syncthreads();
  if (t < 256) {
    float M = sm_m[0][t], S = sm_s[0][t];
    float mo = sm_m[1][t], so = sm_s[1][t];
    float nm = fmaxf(M, mo);
    S = S * __expf(M - nm) + so * __expf(mo - nm);
    M = nm;
    const int grow = m0 + t;
    pm[(size_t)grow * PLD + (w >> 1)] = M;
    ps[(size_t)grow * PLD + (w >> 1)] = S;
  }
}

// ================= final subtract with fused per-row lse =================
__global__ __launch_bounds__(256) void k_out(const bf16* __restrict__ z,
                                             const float* __restrict__ pm,
                                             const float* __restrict__ ps,
                                             float* __restrict__ out) {
  const int b = blockIdx.y;
  const int t = threadIdx.x;
  __shared__ float lsev;
  if (t < 64) {
    float m = -1e30f, s = 0.f;
    for (int tt = t; tt < NT; tt += 64) {
      float mo = pm[(size_t)b * PLD + tt], so = ps[(size_t)b * PLD + tt];
      float nm = fmaxf(m, mo);
      s = s * __expf(m - nm) + so * __expf(mo - nm);
      m = nm;
    }
#pragma unroll
    for (int off = 32; off; off >>= 1) {
      float mo = __shfl_xor(m, off), so = __shfl_xor(s, off);
      float nm = fmaxf(m, mo);
      s = s * __expf(m - nm) + so * __expf(mo - nm);
      m = nm;
    }
    if (t == 0) lsev = logf(s) + m;
  }
  __syncthreads();
  const float l = lsev;
  const int c = (blockIdx.x * 256 + t) * 4;
  if (c >= VV) return;
  const bf16* zr = z + (size_t)b * ZS;
  float* orow = out + (size_t)b * VV;
  if (c + 4 <= VV) {
    bf16x4v v = *(const bf16x4v*)(zr + c);
    float4 o = make_float4((float)v[0] - l, (float)v[1] - l, (float)v[2] - l, (float)v[3] - l);
    *(float4*)(orow + c) = o;
  } else {
    for (int e = c; e < VV; ++e) orow[e] = (float)zr[e] - l;
  }
}

// ================= fallback (small ws): standalone kernels =================

template <int BLAYOUT, int OMODE>
__global__ __launch_bounds__(256, 3) void k_gemm(const bf16* A, const float* Bm, const float* bias,
                                                 void* Cout, int N, int K, int ldc, int lda,
                                                 int ldb) {
  __shared__ __align__(16) char sm[10240];
  dev_gemm<BLAYOUT, OMODE>(sm, blockIdx.y * gridDim.x + blockIdx.x, gridDim.x, A, Bm, bias, Cout,
                           N, K, ldc, lda, ldb);
}

__global__ __launch_bounds__(512) void k_lsm(const bf16* __restrict__ z, float* __restrict__ out) {
  const int b = blockIdx.x, t = threadIdx.x;
  const bf16* zr = z + (size_t)b * ZS;
  float m = -1e30f, s = 0.f;
  for (int c = t; c < 6282; c += 512) {
    bf16x8 v = *(const bf16x8*)(zr + (size_t)c * 8);
#pragma unroll
    for (int e = 0; e < 8; ++e) {
      float x = (float)v[e];
      float nm = fmaxf(m, x);
      s = s * __expf(m - nm) + __expf(x - nm);
      m = nm;
    }
  }
  if (t == 0) {
    float x = (float)zr[VV - 1];
    float nm = fmaxf(m, x);
    s = s * __expf(m - nm) + __expf(x - nm);
    m = nm;
  }
  for (int off = 32; off; off >>= 1) {
    float mo = __shfl_xor(m, off), so = __shfl_xor(s, off);
    float nm = fmaxf(m, mo);
    s = s * __expf(m - nm) + so * __expf(mo - nm);
    m = nm;
  }
  __shared__ float ms[8], ss[8];
  if ((t & 63) == 0) { ms[t >> 6] = m; ss[t >> 6] = s; }
  __syncthreads();
  if (t == 0) {
    float M = ms[0], S = ss[0];
    for (int wv = 1; wv < 8; ++wv) {
      float nm = fmaxf(M, ms[wv]);
      S = S * __expf(M - nm) + ss[wv] * __expf(ms[wv] - nm);
      M = nm;
    }
    ss[0] = logf(S) + M;
  }
  __syncthreads();
  const float lse = ss[0];
  float* orow = out + (size_t)b * VV;
  for (int v = t; v < VV; v += 512) orow[v] = (float)zr[v] - lse;
}

__global__ void k_convertG(const float* emb, const float* h0, bf16* A_cat, bf16* cat2) {
  dev_convert(blockIdx.x, emb, h0, A_cat, cat2);
}
__global__ void k_smaxG(const float* sp, const float* attn_b, float* attn_out, bf16* aw_b) {
  dev_smax(blockIdx.x, sp, attn_b, attn_out, aw_b);
}
__global__ void k_gruG(const float* gi, const float* gh, const float* h0, float* h1_out,
                       bf16* h1b) {
  dev_gru(blockIdx.x, gi, gh, h0, h1_out, h1b);
}

// ================= host =================

extern "C" void kernel_launch(void* const* d_in, const int* in_sizes, int n_in,
                              void* d_out, int out_size, void* d_ws, size_t ws_size,
                              hipStream_t stream) {
  const float* emb    = (const float*)d_in[0];
  const float* h0     = (const float*)d_in[1];
  const float* enc    = (const float*)d_in[2];
  const float* attn_W = (const float*)d_in[3];
  const float* attn_b = (const float*)d_in[4];
  const float* comb_W = (const float*)d_in[5];
  const float* comb_b = (const float*)d_in[6];
  const float* W_ih   = (const float*)d_in[7];
  const float* W_hh   = (const float*)d_in[8];
  const float* b_ih   = (const float*)d_in[9];
  const float* b_hh   = (const float*)d_in[10];
  const float* out_W  = (const float*)d_in[11];
  const float* out_b  = (const float*)d_in[12];

  float* out      = (float*)d_out;
  float* h1out    = out + (size_t)BB * VV;
  float* attn_out = h1out + (size_t)BB * HH;

  char* ws = (char*)d_ws;
  bf16* A_cat  = (bf16*)(ws);
  bf16* cat2   = (bf16*)(ws + 2097152);
  bf16* x      = (bf16*)(ws + 4194304);
  bf16* h1b    = (bf16*)(ws + 5242880);
  float* gi    = (float*)(ws + 6291456);             // fallback only
  float* gh    = (float*)(ws + 12582912);            // fallback only
  float* sp    = (float*)(ws + 18874368);
  bf16* aw_b   = (bf16*)(ws + 19398656);
  bf16* z      = (bf16*)(ws + 19464192);             // 512 x ZS bf16 (51.5 MB)
  bf16* Wt     = (bf16*)(ws + 70934528);             // 50432 x 1024 bf16 (103.3 MB)
  float* pm    = (float*)(ws + 174219264);           // 512 x 400 f32
  float* ps    = (float*)(ws + 175038464);           // 512 x 400 f32
  float* combp = (float*)(ws + 175857664);           // 8 x 512 x 1024 f32 (16.8 MB)
  float* ghp   = (float*)(ws + 192634880);           // 8 x 512 x 3072 f32 (50.3 MB)
  float* gip   = (float*)(ws + 242966528);           // 8 x 512 x 3072 f32 (50.3 MB)
  const size_t WS_NEED = 293298176ull;

  if (ws_size >= WS_NEED) {
    int off = 0;
    k_head<<<2560 + 3400, 256, 0, stream>>>(emb, h0, attn_W, sp, A_cat, cat2, out_W, Wt, off);
    off += 3400;
    k_sapp_gh<<<32 + 96 * SK, 256, 0, stream>>>(sp, attn_b, attn_out, enc, A_cat, cat2, W_hh,
                                                ghp);
    k_fat_comb8<<<32 * SK + 2400, 256, 0, stream>>>(A_cat, comb_W, combp, out_W, Wt, off);
    off += 2400;
    k_fat_xred<<<2048 + 2200, 256, 0, stream>>>(combp, comb_b, x, out_W, Wt, off); off += 2200;
    k_fat_gi8<<<96 * SK + 2400, 256, 0, stream>>>(x, W_ih, gip, out_W, Wt, off); off += 2400;
    k_fat_gru8<<<2048 + (TRB - off), 256, 0, stream>>>(gip, ghp, b_ih, b_hh, h0, h1out, h1b,
                                                       out_W, Wt, off);
    k_gemm_big<<<2 * NT, 512, 0, stream>>>(h1b, Wt, out_b, z, pm, ps);
    k_out<<<dim3(50, BB), 256, 0, stream>>>(z, pm, ps, out);
  } else {
    k_convertG<<<BB * HH / 256, 256, 0, stream>>>(emb, h0, A_cat, cat2);
    k_gemm<0, 0><<<dim3(2, 4), 256, 0, stream>>>(cat2, attn_W, nullptr, sp, LL, 512, LL, 2048, 0);
    k_smaxG<<<BB / 4, 256, 0, stream>>>(sp, attn_b, attn_out, aw_b);
    k_gemm<0, 2><<<dim3(32, 1), 256, 0, stream>>>(aw_b, enc, nullptr, A_cat + 1024, HH, LL, 2048, LL, 0);
    k_gemm<0, 1><<<dim3(32, 1), 256, 0, stream>>>(A_cat, comb_W, comb_b, x, HH, 2 * HH, HH, 2 * HH, 0);
    k_gemm<1, 0><<<dim3(96, 1), 256, 0, stream>>>(x, W_ih, b_ih, gi, 3 * HH, HH, 3 * HH, HH, HH);
    k_gemm<1, 0><<<dim3(96, 1), 256, 0, stream>>>(cat2 + 1024, W_hh, b_hh, gh, 3 * HH, HH, 3 * HH, 2048, HH);
    k_gruG<<<BB * HH / 256, 256, 0, stream>>>(gi, gh, h0, h1out, h1b);
    k_gemm<0, 2><<<dim3(2 * ((VV + 63) / 64), 1), 256, 0, stream>>>(h1b, out_W, out_b, z, VV, HH, ZS, HH, 0);
    k_lsm<<<BB, 512, 0, stream>>>(z, out);
  }
}

// Round 20
// 324.666 us; speedup vs baseline: 1.1819x; 1.0433x over previous
//
#include <hip/hip_runtime.h>

#define HH 1024
#define VV 50257
#define ZS 50264    // padded z row stride
#define NPAD2 50432 // Wt rows = 788*64
#define NT 394      // big-gemm n-tiles (128 wide)
#define PLD 400
#define LL 64
#define BB 512
#define TRB 12608   // transpose blocks: 788 c-tiles * 16 k-tiles

typedef __bf16 bf16;
typedef bf16 bf16x8 __attribute__((ext_vector_type(8)));
typedef bf16 bf16x4v __attribute__((ext_vector_type(4)));
typedef float f32x4 __attribute__((ext_vector_type(4)));
typedef unsigned uint4v __attribute__((ext_vector_type(4)));

typedef __attribute__((address_space(1))) const unsigned int g_u32;
typedef __attribute__((address_space(3))) unsigned int l_u32;

static __device__ __forceinline__ bf16 f2bf(float f) {
  unsigned u = __builtin_bit_cast(unsigned, f);
  unsigned r = u + 0x7fffu + ((u >> 16) & 1u);
  unsigned short h = (unsigned short)(r >> 16);
  return __builtin_bit_cast(bf16, h);
}

static __device__ __forceinline__ unsigned cvt_pk(float lo, float hi) {
  unsigned r;
  asm("v_cvt_pk_bf16_f32 %0, %1, %2" : "=v"(r) : "v"(lo), "v"(hi));
  return r;
}

// ================= device pieces =================

// transpose+convert one 64x64 tile of out_W fp32[1024][50257] -> Wt bf16[50432][1024]
static __device__ void dev_tr(char* smemraw, int tb, const float* __restrict__ W,
                              bf16* __restrict__ Wt) {
  float(*T)[65] = (float(*)[65])smemraw;
  const int ct = tb % 788, kt = tb / 788;
  const int c0 = ct * 64, k0 = kt * 64;
  const int t = threadIdx.x;
  const int cc = t & 63, k4 = t >> 6;
  const int c = c0 + cc;
  if (c0 + 63 < VV) {
#pragma unroll
    for (int j = 0; j < 16; ++j)
      T[cc][k4 * 16 + j] = W[(size_t)(k0 + k4 * 16 + j) * VV + c];
  } else {
    const bool ok = c < VV;
#pragma unroll
    for (int j = 0; j < 16; ++j)
      T[cc][k4 * 16 + j] = ok ? W[(size_t)(k0 + k4 * 16 + j) * VV + c] : 0.f;
  }
  __syncthreads();
  const int cc2 = t >> 3, k8 = (t & 7) * 8;
#pragma unroll
  for (int r = 0; r < 2; ++r) {
    const int row = cc2 + 32 * r;
    float v[8];
#pragma unroll
    for (int e = 0; e < 8; ++e) v[e] = T[row][k8 + e];
    uint4v p = {cvt_pk(v[0], v[1]), cvt_pk(v[2], v[3]), cvt_pk(v[4], v[5]), cvt_pk(v[6], v[7])};
    *(uint4v*)(Wt + (size_t)(c0 + row) * HH + k0 + k8) = p;
  }
}

// generic small GEMM (R11-verified BK=32) + ldb for split-K BLAYOUT1.
// C(512 x N) = A(512 x Ktot bf16, lda) * B + bias; kb = bid/nwgx selects K-chunk of size K.
template <int BLAYOUT, int OMODE>
static __device__ void dev_gemm(char* smemraw, int bid, int nwgx,
                                const bf16* __restrict__ A, const float* __restrict__ Bm,
                                const float* __restrict__ bias, void* __restrict__ Cout,
                                int N, int K, int ldc, int lda, int ldb) {
  typedef unsigned short us40[64][40];
  us40* Bs = (us40*)smemraw;  // [2][64][40]
  const int t = threadIdx.x;
  const int kb = bid / nwgx;
  const int bidx = bid % nwgx;
  const int xcd = bidx & 7, jj = bidx >> 3;
  const int q = nwgx >> 3, r = nwgx & 7;
  const int w = (xcd < r ? xcd * (q + 1) : r * (q + 1) + (xcd - r) * q) + jj;
  const int n0 = (w >> 1) * 64;
  const int m0 = (w & 1) * 256;
  const int lane = t & 63, wv = t >> 6;
  const int lg = lane >> 4, lr = lane & 15;

  const bf16* Ap = A + (size_t)(m0 + wv * 64 + lr) * lda + (size_t)kb * K + lg * 8;

  const int sn0 = (BLAYOUT == 0) ? (t & 63) : (t >> 2);
  const int sk0 = (BLAYOUT == 0) ? ((t >> 6) * 8) : ((t & 3) * 8);

  auto stageB = [&](int buf, int k0) {
    if (BLAYOUT == 0) {
      const bool nok = (n0 + sn0) < N;
      const float* bsrc = Bm + (size_t)(kb * K + k0 + sk0) * N + n0 + sn0;
      float v[8];
#pragma unroll
      for (int e = 0; e < 8; ++e) v[e] = nok ? bsrc[(size_t)e * N] : 0.f;
      uint4v p = {cvt_pk(v[0], v[1]), cvt_pk(v[2], v[3]), cvt_pk(v[4], v[5]), cvt_pk(v[6], v[7])};
      *(uint4v*)(&Bs[buf][sn0][sk0]) = p;
    } else {
      const float* bsrc = Bm + (size_t)(n0 + sn0) * ldb + kb * K + k0 + sk0;
      float4 f0 = *(const float4*)(bsrc);
      float4 f1 = *(const float4*)(bsrc + 4);
      uint4v p = {cvt_pk(f0.x, f0.y), cvt_pk(f0.z, f0.w), cvt_pk(f1.x, f1.y), cvt_pk(f1.z, f1.w)};
      *(uint4v*)(&Bs[buf][sn0][sk0]) = p;
    }
  };

  f32x4 acc[4][4] = {};
  bf16x8 a[4], an[4];
#pragma unroll
  for (int i = 0; i < 4; ++i) a[i] = *(const bf16x8*)(Ap + (size_t)i * 16 * lda);

  const int nk = K >> 5;
  int cur = 0;
  stageB(0, 0);

  for (int ik = 0; ik < nk; ++ik) {
    __syncthreads();
    const bool more = (ik + 1 < nk);
    if (more) {
      stageB(cur ^ 1, (ik + 1) * 32);
#pragma unroll
      for (int i = 0; i < 4; ++i)
        an[i] = *(const bf16x8*)(Ap + (size_t)i * 16 * lda + (ik + 1) * 32);
    }
    bf16x8 b[4];
#pragma unroll
    for (int jx = 0; jx < 4; ++jx)
      b[jx] = *(const bf16x8*)(&Bs[cur][jx * 16 + lr][lg * 8]);
#pragma unroll
    for (int i = 0; i < 4; ++i)
#pragma unroll
      for (int jx = 0; jx < 4; ++jx)
        acc[i][jx] = __builtin_amdgcn_mfma_f32_16x16x32_bf16(a[i], b[jx], acc[i][jx], 0, 0, 0);
    if (more) {
#pragma unroll
      for (int i = 0; i < 4; ++i) a[i] = an[i];
    }
    cur ^= 1;
  }

  float bb[4];
#pragma unroll
  for (int jx = 0; jx < 4; ++jx) {
    int col = n0 + 16 * jx + lr;
    bb[jx] = (bias && col < N) ? bias[col] : 0.f;
  }
  float* co_f = (float*)Cout + (size_t)kb * BB * ldc;
  bf16* co_b = (bf16*)Cout;
#pragma unroll
  for (int i = 0; i < 4; ++i)
#pragma unroll
    for (int jx = 0; jx < 4; ++jx) {
      const int col = n0 + 16 * jx + lr;
      if (col < N) {
#pragma unroll
        for (int rr = 0; rr < 4; ++rr) {
          const int row = m0 + wv * 64 + 16 * i + lg * 4 + rr;
          float vvv = acc[i][jx][rr] + bb[jx];
          if (OMODE == 0)
            co_f[(size_t)row * ldc + col] = vvv;
          else if (OMODE == 1)
            co_b[(size_t)row * ldc + col] = f2bf(fmaxf(vvv, 0.f));
          else
            co_b[(size_t)row * ldc + col] = f2bf(vvv);
        }
      }
    }
}

// fused attention softmax + applied GEMM (R6/R8-verified)
static __device__ void dev_sapp(char* smemraw, int bid, const float* __restrict__ sp,
                                const float* __restrict__ attn_b, float* __restrict__ attn_out,
                                const float* __restrict__ enc, bf16* __restrict__ A_cat) {
  bf16(*aw)[72] = (bf16(*)[72])smemraw;                   // [256][72]
  bf16(*Bs)[72] = (bf16(*)[72])(smemraw + 256 * 72 * 2);  // [64][72]
  const int t = threadIdx.x;
  const int mhalf = bid & 1, nblk = bid >> 1;
  const int m0 = mhalf * 256, n0 = nblk * 64;
  const int lane = t & 63, wv = t >> 6;

#pragma unroll 4
  for (int rr = 0; rr < 64; ++rr) {
    const int row = m0 + wv * 64 + rr;
    const size_t idx = (size_t)row * LL + lane;
    float s = sp[idx] + sp[idx + (size_t)BB * LL] + sp[idx + (size_t)2 * BB * LL] +
              sp[idx + (size_t)3 * BB * LL] + attn_b[lane];
    float m = s;
#pragma unroll
    for (int off = 32; off; off >>= 1) m = fmaxf(m, __shfl_xor(m, off));
    float e = __expf(s - m);
    float sum = e;
#pragma unroll
    for (int off = 32; off; off >>= 1) sum += __shfl_xor(sum, off);
    float wvv = e / sum;
    if (nblk == 0) attn_out[idx] = wvv;
    aw[wv * 64 + rr][lane] = f2bf(wvv);
  }
  {
    const int n = t & 63, kb4 = (t >> 6) * 16;
#pragma unroll
    for (int kk = 0; kk < 16; ++kk)
      Bs[n][kb4 + kk] = f2bf(enc[(size_t)(kb4 + kk) * HH + n0 + n]);
  }
  __syncthreads();
  const int lg = lane >> 4, lr = lane & 15;
  f32x4 acc[4][4] = {};
#pragma unroll
  for (int kk = 0; kk < 2; ++kk) {
    bf16x8 a[4], b[4];
#pragma unroll
    for (int i = 0; i < 4; ++i)
      a[i] = *(const bf16x8*)(&aw[wv * 64 + 16 * i + lr][kk * 32 + lg * 8]);
#pragma unroll
    for (int j = 0; j < 4; ++j)
      b[j] = *(const bf16x8*)(&Bs[16 * j + lr][kk * 32 + lg * 8]);
#pragma unroll
    for (int i = 0; i < 4; ++i)
#pragma unroll
      for (int j = 0; j < 4; ++j)
        acc[i][j] = __builtin_amdgcn_mfma_f32_16x16x32_bf16(a[i], b[j], acc[i][j], 0, 0, 0);
  }
#pragma unroll
  for (int i = 0; i < 4; ++i)
#pragma unroll
    for (int j = 0; j < 4; ++j)
#pragma unroll
      for (int rr = 0; rr < 4; ++rr) {
        const int row = m0 + wv * 64 + 16 * i + lg * 4 + rr;
        A_cat[(size_t)row * 2048 + 1024 + n0 + 16 * j + lr] = f2bf(acc[i][j][rr]);
      }
}

static __device__ void dev_convert(int bid, const float* __restrict__ emb,
                                   const float* __restrict__ h0, bf16* __restrict__ A_cat,
                                   bf16* __restrict__ cat2) {
  int i = bid * 256 + threadIdx.x;
  int b = i >> 10, h = i & 1023;
  bf16 e = f2bf(emb[i]);
  A_cat[(size_t)b * 2048 + h] = e;
  cat2[(size_t)b * 2048 + h] = e;
  cat2[(size_t)b * 2048 + 1024 + h] = f2bf(h0[i]);
}

static __device__ void dev_smax(int bid, const float* __restrict__ sp,
                                const float* __restrict__ attn_b, float* __restrict__ attn_out,
                                bf16* __restrict__ aw_b) {
  const int t = threadIdx.x;
  const int row = bid * 4 + (t >> 6);
  const int l = t & 63;
  const size_t idx = (size_t)row * LL + l;
  float s = sp[idx] + sp[idx + (size_t)BB * LL] + sp[idx + (size_t)2 * BB * LL] +
            sp[idx + (size_t)3 * BB * LL] + attn_b[l];
  float m = s;
#pragma unroll
  for (int off = 32; off; off >>= 1) m = fmaxf(m, __shfl_xor(m, off));
  float e = __expf(s - m);
  float sum = e;
#pragma unroll
  for (int off = 32; off; off >>= 1) sum += __shfl_xor(sum, off);
  float wv = e / sum;
  attn_out[idx] = wv;
  aw_b[idx] = f2bf(wv);
}

// gru from split-K partials: h1 from gi parts (4) + b_ih, gh parts (4) + b_hh
static __device__ void dev_gru4(int bid, const float* __restrict__ gip,
                                const float* __restrict__ ghp, const float* __restrict__ b_ih,
                                const float* __restrict__ b_hh, const float* __restrict__ h0,
                                float* __restrict__ h1_out, bf16* __restrict__ h1b) {
  int i = bid * 256 + threadIdx.x;
  int b = i >> 10, h = i & 1023;
  size_t base = (size_t)b * 3072;
  const size_t PS = (size_t)BB * 3072;
  float ir = b_ih[h], iz = b_ih[1024 + h], in_ = b_ih[2048 + h];
  float hr = b_hh[h], hz = b_hh[1024 + h], hn = b_hh[2048 + h];
#pragma unroll
  for (int p = 0; p < 4; ++p) {
    ir += gip[p * PS + base + h];
    iz += gip[p * PS + base + 1024 + h];
    in_ += gip[p * PS + base + 2048 + h];
    hr += ghp[p * PS + base + h];
    hz += ghp[p * PS + base + 1024 + h];
    hn += ghp[p * PS + base + 2048 + h];
  }
  float r = 1.f / (1.f + __expf(-(ir + hr)));
  float z = 1.f / (1.f + __expf(-(iz + hz)));
  float n = tanhf(in_ + r * hn);
  float h1 = (1.f - z) * n + z * h0[i];
  h1_out[i] = h1;
  h1b[i] = f2bf(h1);
}

static __device__ void dev_gru(int bid, const float* __restrict__ gi, const float* __restrict__ gh,
                               const float* __restrict__ h0, float* __restrict__ h1_out,
                               bf16* __restrict__ h1b) {
  int i = bid * 256 + threadIdx.x;
  int b = i >> 10, h = i & 1023;
  size_t base = (size_t)b * 3072;
  float ir = gi[base + h], iz = gi[base + 1024 + h], in_ = gi[base + 2048 + h];
  float hr = gh[base + h], hz = gh[base + 1024 + h], hn = gh[base + 2048 + h];
  float r = 1.f / (1.f + __expf(-(ir + hr)));
  float z = 1.f / (1.f + __expf(-(iz + hz)));
  float n = tanhf(in_ + r * hn);
  float h1 = (1.f - z) * n + z * h0[i];
  h1_out[i] = h1;
  h1b[i] = f2bf(h1);
}

// x = relu(sum comb partials + comb_b) -> bf16
static __device__ void dev_xred(int bid, const float* __restrict__ cp,
                                const float* __restrict__ comb_b, bf16* __restrict__ x) {
  int i = bid * 256 + threadIdx.x;  // < 512*1024
  int col = i & 1023;
  const size_t PS = (size_t)BB * HH;
  float s = cp[i] + cp[PS + i] + cp[2 * PS + i] + cp[3 * PS + i] + comb_b[col];
  x[i] = f2bf(fmaxf(s, 0.f));
}

// ================= fast-path launches =================

// L1: fp32 scores (R9-verified) + convert + tr slice
__global__ __launch_bounds__(256) void k_head(const float* __restrict__ emb,
                                              const float* __restrict__ h0,
                                              const float* __restrict__ attn_W,
                                              float* __restrict__ sp, bf16* __restrict__ A_cat,
                                              bf16* __restrict__ cat2,
                                              const float* __restrict__ W, bf16* __restrict__ Wt,
                                              int trOff) {
  __shared__ __align__(16) char sm[16640];
  const int bid = blockIdx.x;
  if (bid < 512) {
    const int wv = threadIdx.x >> 6, lane = threadIdx.x & 63;
    const int rq = bid & 127, kc = bid >> 7;
    const int row = rq * 4 + wv;
    const float* Ar = (kc < 2) ? (emb + (size_t)row * HH + kc * 512)
                               : (h0 + (size_t)row * HH + (kc - 2) * 512);
    const float* Wb = attn_W + (size_t)(kc * 512) * LL + lane;
    float acc = 0.f;
#pragma unroll 4
    for (int k8 = 0; k8 < 64; ++k8) {
      float4 a0 = *(const float4*)(Ar + k8 * 8);
      float4 a1 = *(const float4*)(Ar + k8 * 8 + 4);
      const float* wp = Wb + (size_t)k8 * 8 * LL;
      acc = fmaf(a0.x, wp[0], acc);
      acc = fmaf(a0.y, wp[LL], acc);
      acc = fmaf(a0.z, wp[2 * LL], acc);
      acc = fmaf(a0.w, wp[3 * LL], acc);
      acc = fmaf(a1.x, wp[4 * LL], acc);
      acc = fmaf(a1.y, wp[5 * LL], acc);
      acc = fmaf(a1.z, wp[6 * LL], acc);
      acc = fmaf(a1.w, wp[7 * LL], acc);
    }
    sp[((size_t)kc * BB + row) * LL + lane] = acc;
  } else if (bid < 2560) {
    dev_convert(bid - 512, emb, h0, A_cat, cat2);
  } else {
    int tb = trOff + bid - 2560;
    if (tb < TRB) dev_tr(sm, tb, W, Wt);
  }
}

// L2: sapp (32) + gh split-K=4 (384) — no tr (46KB LDS)
__global__ __launch_bounds__(256) void k_sapp_gh(const float* sp, const float* attn_b,
                                                 float* attn_out, const float* enc, bf16* A_cat,
                                                 const bf16* cat2, const float* W_hh,
                                                 float* ghp) {
  __shared__ __align__(16) char sm[46080];
  const int bid = blockIdx.x;
  if (bid < 32) dev_sapp(sm, bid, sp, attn_b, attn_out, enc, A_cat);
  else dev_gemm<1, 0>(sm, bid - 32, 96, cat2 + 1024, W_hh, nullptr, ghp, 3 * HH, 256, 3 * HH,
                      2048, HH);
}

// L3: comb split-K=4 (128) + tr
__global__ __launch_bounds__(256, 3) void k_fat_comb4(const bf16* A_cat, const float* comb_W,
                                                      float* combp, const float* W, bf16* Wt,
                                                      int trOff) {
  __shared__ __align__(16) char sm[16640];
  const int bid = blockIdx.x;
  if (bid < 128)
    dev_gemm<0, 0>(sm, bid, 32, A_cat, comb_W, nullptr, combp, HH, 512, HH, 2048, 0);
  else { int tb = trOff + bid - 128; if (tb < TRB) dev_tr(sm, tb, W, Wt); }
}

// L4: x reduce (2048) + tr
__global__ __launch_bounds__(256) void k_fat_xred(const float* combp, const float* comb_b,
                                                  bf16* x, const float* W, bf16* Wt, int trOff) {
  __shared__ __align__(16) char sm[16640];
  const int bid = blockIdx.x;
  if (bid < 2048) dev_xred(bid, combp, comb_b, x);
  else { int tb = trOff + bid - 2048; if (tb < TRB) dev_tr(sm, tb, W, Wt); }
}

// L5: gi split-K=4 (384) + tr
__global__ __launch_bounds__(256, 3) void k_fat_gi4(const bf16* x, const float* W_ih, float* gip,
                                                    const float* W, bf16* Wt, int trOff) {
  __shared__ __align__(16) char sm[16640];
  const int bid = blockIdx.x;
  if (bid < 384)
    dev_gemm<1, 0>(sm, bid, 96, x, W_ih, nullptr, gip, 3 * HH, 256, 3 * HH, HH, HH);
  else { int tb = trOff + bid - 384; if (tb < TRB) dev_tr(sm, tb, W, Wt); }
}

// L6: gru from partials (2048) + tr
__global__ __launch_bounds__(256) void k_fat_gru4(const float* gip, const float* ghp,
                                                  const float* b_ih, const float* b_hh,
                                                  const float* h0, float* h1_out, bf16* h1b,
                                                  const float* W, bf16* Wt, int trOff) {
  __shared__ __align__(16) char sm[16640];
  const int bid = blockIdx.x;
  if (bid < 2048) dev_gru4(bid, gip, ghp, b_ih, b_hh, h0, h1_out, h1b);
  else { int tb = trOff + bid - 2048; if (tb < TRB) dev_tr(sm, tb, W, Wt); }
}

// ===== big GEMM (R11-verified): 256x128 tile, 8 waves, NBUF=2, 2 blocks/CU =====
__global__ __launch_bounds__(512, 4) void k_gemm_big(const bf16* __restrict__ A,
                                                     const bf16* __restrict__ Bt,
                                                     const float* __restrict__ bias,
                                                     bf16* __restrict__ C,
                                                     float* __restrict__ pm,
                                                     float* __restrict__ ps) {
  __shared__ __align__(16) bf16 Asm[2][8192];
  __shared__ __align__(16) bf16 Bsm[2][4096];
  __shared__ float sm_m[2][256], sm_s[2][256];
  const int t = threadIdx.x;
  const int bid = blockIdx.x;
  const int nwg = gridDim.x;  // 788
  const int xcd = bid & 7, jj = bid >> 3;
  const int q = nwg >> 3, r = nwg & 7;
  const int w = (xcd < r ? xcd * (q + 1) : r * (q + 1) + (xcd - r) * q) + jj;
  const int m0 = (w & 1) * 256;
  const int n0 = (w >> 1) * 128;
  const int lane = t & 63, wv = t >> 6;
  const int wvm = wv >> 1, wvn = wv & 1;
  const int lg = lane >> 4, lr = lane & 15;

  const int srow = lane >> 2;
  const int skk = (((lane & 3) ^ ((lane >> 3) & 3))) * 8;
  const bf16* Aa0 = A + (size_t)(m0 + wv * 32 + srow) * HH + skk;
  const bf16* Aa1 = Aa0 + (size_t)16 * HH;
  const bf16* Bb0 = Bt + (size_t)(n0 + wv * 16 + srow) * HH + skk;

  auto stage = [&](int buf, int koff) {
    __builtin_amdgcn_global_load_lds((g_u32*)(Aa0 + koff), (l_u32*)(&Asm[buf][wv * 1024]), 16, 0, 0);
    __builtin_amdgcn_global_load_lds((g_u32*)(Aa1 + koff), (l_u32*)(&Asm[buf][wv * 1024 + 512]), 16, 0, 0);
    __builtin_amdgcn_global_load_lds((g_u32*)(Bb0 + koff), (l_u32*)(&Bsm[buf][wv * 512]), 16, 0, 0);
  };

  f32x4 acc[4][4] = {};
  stage(0, 0);
  __syncthreads();
  int cur = 0;
  const int nk = HH / 32;
  const int rga = (lr >> 1) & 3;
  for (int ik = 0; ik < nk; ++ik) {
    if (ik + 1 < nk) stage(cur ^ 1, (ik + 1) * 32);
    bf16x8 a[4], b[4];
#pragma unroll
    for (int i = 0; i < 4; ++i)
      a[i] = *(const bf16x8*)(&Asm[cur][(wvm * 64 + 16 * i + lr) * 32 + ((lg ^ rga) * 8)]);
#pragma unroll
    for (int j = 0; j < 4; ++j)
      b[j] = *(const bf16x8*)(&Bsm[cur][(wvn * 64 + 16 * j + lr) * 32 + ((lg ^ rga) * 8)]);
#pragma unroll
    for (int i = 0; i < 4; ++i)
#pragma unroll
      for (int j = 0; j < 4; ++j)
        acc[i][j] = __builtin_amdgcn_mfma_f32_16x16x32_bf16(a[i], b[j], acc[i][j], 0, 0, 0);
    __syncthreads();
    cur ^= 1;
  }

  float bb[4];
#pragma unroll
  for (int j = 0; j < 4; ++j) {
    const int col = n0 + wvn * 64 + 16 * j + lr;
    bb[j] = (col < VV) ? bias[col] : 0.f;
  }
#pragma unroll
  for (int i = 0; i < 4; ++i)
#pragma unroll
    for (int j = 0; j < 4; ++j)
#pragma unroll
      for (int rr = 0; rr < 4; ++rr) acc[i][j][rr] += bb[j];

#pragma unroll
  for (int i = 0; i < 4; ++i)
#pragma unroll
    for (int j = 0; j < 4; ++j) {
      const int col = n0 + wvn * 64 + 16 * j + lr;
      if (col < VV) {
#pragma unroll
        for (int rr = 0; rr < 4; ++rr) {
          const int row = m0 + wvm * 64 + 16 * i + lg * 4 + rr;
          C[(size_t)row * ZS + col] = f2bf(acc[i][j][rr]);
        }
      }
    }

#pragma unroll
  for (int i = 0; i < 4; ++i)
#pragma unroll
    for (int rr = 0; rr < 4; ++rr) {
      float mr = -1e30f;
#pragma unroll
      for (int j = 0; j < 4; ++j)
        if (n0 + wvn * 64 + 16 * j + lr < VV) mr = fmaxf(mr, acc[i][j][rr]);
      float sr = 0.f;
#pragma unroll
      for (int j = 0; j < 4; ++j)
        if (n0 + wvn * 64 + 16 * j + lr < VV) sr += __expf(acc[i][j][rr] - mr);
#pragma unroll
      for (int off = 1; off < 16; off <<= 1) {
        float mo = __shfl_xor(mr, off), so = __shfl_xor(sr, off);
        float nm = fmaxf(mr, mo);
        sr = sr * __expf(mr - nm) + so * __expf(mo - nm);
        mr = nm;
      }
      if (lr == 0) {
        const int row = wvm * 64 + 16 * i + lg * 4 + rr;
        sm_m[wvn][row] = mr;
        sm_s[wvn][row] = sr;
      }
    }
  __syncthreads();
  if (t < 256) {
    float M = sm_m[0][t], S = sm_s[0][t];
    float mo = sm_m[1][t], so = sm_s[1][t];
    float nm = fmaxf(M, mo);
    S = S * __expf(M - nm) + so * __expf(mo - nm);
    M = nm;
    const int grow = m0 + t;
    pm[(size_t)grow * PLD + (w >> 1)] = M;
    ps[(size_t)grow * PLD + (w >> 1)] = S;
  }
}

// ================= final subtract with fused per-row lse =================
__global__ __launch_bounds__(256) void k_out(const bf16* __restrict__ z,
                                             const float* __restrict__ pm,
                                             const float* __restrict__ ps,
                                             float* __restrict__ out) {
  const int b = blockIdx.y;
  const int t = threadIdx.x;
  __shared__ float lsev;
  if (t < 64) {
    float m = -1e30f, s = 0.f;
    for (int tt = t; tt < NT; tt += 64) {
      float mo = pm[(size_t)b * PLD + tt], so = ps[(size_t)b * PLD + tt];
      float nm = fmaxf(m, mo);
      s = s * __expf(m - nm) + so * __expf(mo - nm);
      m = nm;
    }
#pragma unroll
    for (int off = 32; off; off >>= 1) {
      float mo = __shfl_xor(m, off), so = __shfl_xor(s, off);
      float nm = fmaxf(m, mo);
      s = s * __expf(m - nm) + so * __expf(mo - nm);
      m = nm;
    }
    if (t == 0) lsev = logf(s) + m;
  }
  __syncthreads();
  const float l = lsev;
  const int c = (blockIdx.x * 256 + t) * 4;
  if (c >= VV) return;
  const bf16* zr = z + (size_t)b * ZS;
  float* orow = out + (size_t)b * VV;
  if (c + 4 <= VV) {
    bf16x4v v = *(const bf16x4v*)(zr + c);
    float4 o = make_float4((float)v[0] - l, (float)v[1] - l, (float)v[2] - l, (float)v[3] - l);
    *(float4*)(orow + c) = o;
  } else {
    for (int e = c; e < VV; ++e) orow[e] = (float)zr[e] - l;
  }
}

// ================= fallback (small ws): standalone kernels =================

template <int BLAYOUT, int OMODE>
__global__ __launch_bounds__(256, 3) void k_gemm(const bf16* A, const float* Bm, const float* bias,
                                                 void* Cout, int N, int K, int ldc, int lda,
                                                 int ldb) {
  __shared__ __align__(16) char sm[10240];
  dev_gemm<BLAYOUT, OMODE>(sm, blockIdx.y * gridDim.x + blockIdx.x, gridDim.x, A, Bm, bias, Cout,
                           N, K, ldc, lda, ldb);
}

__global__ __launch_bounds__(512) void k_lsm(const bf16* __restrict__ z, float* __restrict__ out) {
  const int b = blockIdx.x, t = threadIdx.x;
  const bf16* zr = z + (size_t)b * ZS;
  float m = -1e30f, s = 0.f;
  for (int c = t; c < 6282; c += 512) {
    bf16x8 v = *(const bf16x8*)(zr + (size_t)c * 8);
#pragma unroll
    for (int e = 0; e < 8; ++e) {
      float x = (float)v[e];
      float nm = fmaxf(m, x);
      s = s * __expf(m - nm) + __expf(x - nm);
      m = nm;
    }
  }
  if (t == 0) {
    float x = (float)zr[VV - 1];
    float nm = fmaxf(m, x);
    s = s * __expf(m - nm) + __expf(x - nm);
    m = nm;
  }
  for (int off = 32; off; off >>= 1) {
    float mo = __shfl_xor(m, off), so = __shfl_xor(s, off);
    float nm = fmaxf(m, mo);
    s = s * __expf(m - nm) + so * __expf(mo - nm);
    m = nm;
  }
  __shared__ float ms[8], ss[8];
  if ((t & 63) == 0) { ms[t >> 6] = m; ss[t >> 6] = s; }
  __syncthreads();
  if (t == 0) {
    float M = ms[0], S = ss[0];
    for (int wv = 1; wv < 8; ++wv) {
      float nm = fmaxf(M, ms[wv]);
      S = S * __expf(M - nm) + ss[wv] * __expf(ms[wv] - nm);
      M = nm;
    }
    ss[0] = logf(S) + M;
  }
  __syncthreads();
  const float lse = ss[0];
  float* orow = out + (size_t)b * VV;
  for (int v = t; v < VV; v += 512) orow[v] = (float)zr[v] - lse;
}

__global__ void k_convertG(const float* emb, const float* h0, bf16* A_cat, bf16* cat2) {
  dev_convert(blockIdx.x, emb, h0, A_cat, cat2);
}
__global__ void k_smaxG(const float* sp, const float* attn_b, float* attn_out, bf16* aw_b) {
  dev_smax(blockIdx.x, sp, attn_b, attn_out, aw_b);
}
__global__ void k_gruG(const float* gi, const float* gh, const float* h0, float* h1_out,
                       bf16* h1b) {
  dev_gru(blockIdx.x, gi, gh, h0, h1_out, h1b);
}

// ================= host =================

extern "C" void kernel_launch(void* const* d_in, const int* in_sizes, int n_in,
                              void* d_out, int out_size, void* d_ws, size_t ws_size,
                              hipStream_t stream) {
  const float* emb    = (const float*)d_in[0];
  const float* h0     = (const float*)d_in[1];
  const float* enc    = (const float*)d_in[2];
  const float* attn_W = (const float*)d_in[3];
  const float* attn_b = (const float*)d_in[4];
  const float* comb_W = (const float*)d_in[5];
  const float* comb_b = (const float*)d_in[6];
  const float* W_ih   = (const float*)d_in[7];
  const float* W_hh   = (const float*)d_in[8];
  const float* b_ih   = (const float*)d_in[9];
  const float* b_hh   = (const float*)d_in[10];
  const float* out_W  = (const float*)d_in[11];
  const float* out_b  = (const float*)d_in[12];

  float* out      = (float*)d_out;
  float* h1out    = out + (size_t)BB * VV;
  float* attn_out = h1out + (size_t)BB * HH;

  char* ws = (char*)d_ws;
  bf16* A_cat  = (bf16*)(ws);
  bf16* cat2   = (bf16*)(ws + 2097152);
  bf16* x      = (bf16*)(ws + 4194304);
  bf16* h1b    = (bf16*)(ws + 5242880);
  float* gi    = (float*)(ws + 6291456);             // fallback only
  float* gh    = (float*)(ws + 12582912);            // fallback only
  float* sp    = (float*)(ws + 18874368);
  bf16* aw_b   = (bf16*)(ws + 19398656);
  bf16* z      = (bf16*)(ws + 19464192);             // 512 x ZS bf16 (51.5 MB)
  bf16* Wt     = (bf16*)(ws + 70934528);             // 50432 x 1024 bf16 (103.3 MB)
  float* pm    = (float*)(ws + 174219264);           // 512 x 400 f32
  float* ps    = (float*)(ws + 175038464);           // 512 x 400 f32
  float* combp = (float*)(ws + 175857664);           // 4 x 512 x 1024 f32 (8.4 MB)
  float* ghp   = (float*)(ws + 184246272);           // 4 x 512 x 3072 f32 (25.2 MB)
  float* gip   = (float*)(ws + 209412096);           // 4 x 512 x 3072 f32 (25.2 MB)
  const size_t WS_NEED = 234577920ull;

  if (ws_size >= WS_NEED) {
    int off = 0;
    k_head<<<2560 + 3400, 256, 0, stream>>>(emb, h0, attn_W, sp, A_cat, cat2, out_W, Wt, off);
    off += 3400;
    k_sapp_gh<<<416, 256, 0, stream>>>(sp, attn_b, attn_out, enc, A_cat, cat2, W_hh, ghp);
    k_fat_comb4<<<128 + 2400, 256, 0, stream>>>(A_cat, comb_W, combp, out_W, Wt, off); off += 2400;
    k_fat_xred<<<2048 + 2200, 256, 0, stream>>>(combp, comb_b, x, out_W, Wt, off); off += 2200;
    k_fat_gi4<<<384 + 2400, 256, 0, stream>>>(x, W_ih, gip, out_W, Wt, off); off += 2400;
    k_fat_gru4<<<2048 + (TRB - off), 256, 0, stream>>>(gip, ghp, b_ih, b_hh, h0, h1out, h1b,
                                                       out_W, Wt, off);
    k_gemm_big<<<2 * NT, 512, 0, stream>>>(h1b, Wt, out_b, z, pm, ps);
    k_out<<<dim3(50, BB), 256, 0, stream>>>(z, pm, ps, out);
  } else {
    k_convertG<<<BB * HH / 256, 256, 0, stream>>>(emb, h0, A_cat, cat2);
    k_gemm<0, 0><<<dim3(2, 4), 256, 0, stream>>>(cat2, attn_W, nullptr, sp, LL, 512, LL, 2048, 0);
    k_smaxG<<<BB / 4, 256, 0, stream>>>(sp, attn_b, attn_out, aw_b);
    k_gemm<0, 2><<<dim3(32, 1), 256, 0, stream>>>(aw_b, enc, nullptr, A_cat + 1024, HH, LL, 2048, LL, 0);
    k_gemm<0, 1><<<dim3(32, 1), 256, 0, stream>>>(A_cat, comb_W, comb_b, x, HH, 2 * HH, HH, 2 * HH, 0);
    k_gemm<1, 0><<<dim3(96, 1), 256, 0, stream>>>(x, W_ih, b_ih, gi, 3 * HH, HH, 3 * HH, HH, HH);
    k_gemm<1, 0><<<dim3(96, 1), 256, 0, stream>>>(cat2 + 1024, W_hh, b_hh, gh, 3 * HH, HH, 3 * HH, 2048, HH);
    k_gruG<<<BB * HH / 256, 256, 0, stream>>>(gi, gh, h0, h1out, h1b);
    k_gemm<0, 2><<<dim3(2 * ((VV + 63) / 64), 1), 256, 0, stream>>>(h1b, out_W, out_b, z, VV, HH, ZS, HH, 0);
    k_lsm<<<BB, 512, 0, stream>>>(z, out);
  }
}

// Round 21
// 324.043 us; speedup vs baseline: 1.1842x; 1.0019x over previous
//
#include <hip/hip_runtime.h>

#define HH 1024
#define VV 50257
#define ZS 50264    // padded z row stride
#define NPAD2 50432 // Wt rows = 788*64
#define NT 394      // big-gemm n-tiles (128 wide)
#define PLD 400
#define LL 64
#define BB 512
#define TRB 12608   // transpose blocks: 788 c-tiles * 16 k-tiles

typedef __bf16 bf16;
typedef bf16 bf16x8 __attribute__((ext_vector_type(8)));
typedef bf16 bf16x4v __attribute__((ext_vector_type(4)));
typedef float f32x4 __attribute__((ext_vector_type(4)));
typedef unsigned uint4v __attribute__((ext_vector_type(4)));

typedef __attribute__((address_space(1))) const unsigned int g_u32;
typedef __attribute__((address_space(3))) unsigned int l_u32;

static __device__ __forceinline__ bf16 f2bf(float f) {
  unsigned u = __builtin_bit_cast(unsigned, f);
  unsigned r = u + 0x7fffu + ((u >> 16) & 1u);
  unsigned short h = (unsigned short)(r >> 16);
  return __builtin_bit_cast(bf16, h);
}

static __device__ __forceinline__ unsigned cvt_pk(float lo, float hi) {
  unsigned r;
  asm("v_cvt_pk_bf16_f32 %0, %1, %2" : "=v"(r) : "v"(lo), "v"(hi));
  return r;
}

// ================= device pieces =================

// transpose+convert one 64x64 tile of out_W fp32[1024][50257] -> Wt bf16[50432][1024]
static __device__ void dev_tr(char* smemraw, int tb, const float* __restrict__ W,
                              bf16* __restrict__ Wt) {
  float(*T)[65] = (float(*)[65])smemraw;
  const int ct = tb % 788, kt = tb / 788;
  const int c0 = ct * 64, k0 = kt * 64;
  const int t = threadIdx.x;
  const int cc = t & 63, k4 = t >> 6;
  const int c = c0 + cc;
  if (c0 + 63 < VV) {
#pragma unroll
    for (int j = 0; j < 16; ++j)
      T[cc][k4 * 16 + j] = W[(size_t)(k0 + k4 * 16 + j) * VV + c];
  } else {
    const bool ok = c < VV;
#pragma unroll
    for (int j = 0; j < 16; ++j)
      T[cc][k4 * 16 + j] = ok ? W[(size_t)(k0 + k4 * 16 + j) * VV + c] : 0.f;
  }
  __syncthreads();
  const int cc2 = t >> 3, k8 = (t & 7) * 8;
#pragma unroll
  for (int r = 0; r < 2; ++r) {
    const int row = cc2 + 32 * r;
    float v[8];
#pragma unroll
    for (int e = 0; e < 8; ++e) v[e] = T[row][k8 + e];
    uint4v p = {cvt_pk(v[0], v[1]), cvt_pk(v[2], v[3]), cvt_pk(v[4], v[5]), cvt_pk(v[6], v[7])};
    *(uint4v*)(Wt + (size_t)(c0 + row) * HH + k0 + k8) = p;
  }
}

// generic small GEMM (R11-verified BK=32) + ldb for split-K BLAYOUT1.
// C(512 x N) = A(512 x Ktot bf16, lda) * B + bias; kb = bid/nwgx selects K-chunk of size K.
template <int BLAYOUT, int OMODE>
static __device__ void dev_gemm(char* smemraw, int bid, int nwgx,
                                const bf16* __restrict__ A, const float* __restrict__ Bm,
                                const float* __restrict__ bias, void* __restrict__ Cout,
                                int N, int K, int ldc, int lda, int ldb) {
  typedef unsigned short us40[64][40];
  us40* Bs = (us40*)smemraw;  // [2][64][40]
  const int t = threadIdx.x;
  const int kb = bid / nwgx;
  const int bidx = bid % nwgx;
  const int xcd = bidx & 7, jj = bidx >> 3;
  const int q = nwgx >> 3, r = nwgx & 7;
  const int w = (xcd < r ? xcd * (q + 1) : r * (q + 1) + (xcd - r) * q) + jj;
  const int n0 = (w >> 1) * 64;
  const int m0 = (w & 1) * 256;
  const int lane = t & 63, wv = t >> 6;
  const int lg = lane >> 4, lr = lane & 15;

  const bf16* Ap = A + (size_t)(m0 + wv * 64 + lr) * lda + (size_t)kb * K + lg * 8;

  const int sn0 = (BLAYOUT == 0) ? (t & 63) : (t >> 2);
  const int sk0 = (BLAYOUT == 0) ? ((t >> 6) * 8) : ((t & 3) * 8);

  auto stageB = [&](int buf, int k0) {
    if (BLAYOUT == 0) {
      const bool nok = (n0 + sn0) < N;
      const float* bsrc = Bm + (size_t)(kb * K + k0 + sk0) * N + n0 + sn0;
      float v[8];
#pragma unroll
      for (int e = 0; e < 8; ++e) v[e] = nok ? bsrc[(size_t)e * N] : 0.f;
      uint4v p = {cvt_pk(v[0], v[1]), cvt_pk(v[2], v[3]), cvt_pk(v[4], v[5]), cvt_pk(v[6], v[7])};
      *(uint4v*)(&Bs[buf][sn0][sk0]) = p;
    } else {
      const float* bsrc = Bm + (size_t)(n0 + sn0) * ldb + kb * K + k0 + sk0;
      float4 f0 = *(const float4*)(bsrc);
      float4 f1 = *(const float4*)(bsrc + 4);
      uint4v p = {cvt_pk(f0.x, f0.y), cvt_pk(f0.z, f0.w), cvt_pk(f1.x, f1.y), cvt_pk(f1.z, f1.w)};
      *(uint4v*)(&Bs[buf][sn0][sk0]) = p;
    }
  };

  f32x4 acc[4][4] = {};
  bf16x8 a[4], an[4];
#pragma unroll
  for (int i = 0; i < 4; ++i) a[i] = *(const bf16x8*)(Ap + (size_t)i * 16 * lda);

  const int nk = K >> 5;
  int cur = 0;
  stageB(0, 0);

  for (int ik = 0; ik < nk; ++ik) {
    __syncthreads();
    const bool more = (ik + 1 < nk);
    if (more) {
      stageB(cur ^ 1, (ik + 1) * 32);
#pragma unroll
      for (int i = 0; i < 4; ++i)
        an[i] = *(const bf16x8*)(Ap + (size_t)i * 16 * lda + (ik + 1) * 32);
    }
    bf16x8 b[4];
#pragma unroll
    for (int jx = 0; jx < 4; ++jx)
      b[jx] = *(const bf16x8*)(&Bs[cur][jx * 16 + lr][lg * 8]);
#pragma unroll
    for (int i = 0; i < 4; ++i)
#pragma unroll
      for (int jx = 0; jx < 4; ++jx)
        acc[i][jx] = __builtin_amdgcn_mfma_f32_16x16x32_bf16(a[i], b[jx], acc[i][jx], 0, 0, 0);
    if (more) {
#pragma unroll
      for (int i = 0; i < 4; ++i) a[i] = an[i];
    }
    cur ^= 1;
  }

  float bb[4];
#pragma unroll
  for (int jx = 0; jx < 4; ++jx) {
    int col = n0 + 16 * jx + lr;
    bb[jx] = (bias && col < N) ? bias[col] : 0.f;
  }
  float* co_f = (float*)Cout + (size_t)kb * BB * ldc;
  bf16* co_b = (bf16*)Cout;
#pragma unroll
  for (int i = 0; i < 4; ++i)
#pragma unroll
    for (int jx = 0; jx < 4; ++jx) {
      const int col = n0 + 16 * jx + lr;
      if (col < N) {
#pragma unroll
        for (int rr = 0; rr < 4; ++rr) {
          const int row = m0 + wv * 64 + 16 * i + lg * 4 + rr;
          float vvv = acc[i][jx][rr] + bb[jx];
          if (OMODE == 0)
            co_f[(size_t)row * ldc + col] = vvv;
          else if (OMODE == 1)
            co_b[(size_t)row * ldc + col] = f2bf(fmaxf(vvv, 0.f));
          else
            co_b[(size_t)row * ldc + col] = f2bf(vvv);
        }
      }
    }
}

// fused attention softmax + applied GEMM (R6/R8-verified)
static __device__ void dev_sapp(char* smemraw, int bid, const float* __restrict__ sp,
                                const float* __restrict__ attn_b, float* __restrict__ attn_out,
                                const float* __restrict__ enc, bf16* __restrict__ A_cat) {
  bf16(*aw)[72] = (bf16(*)[72])smemraw;                   // [256][72]
  bf16(*Bs)[72] = (bf16(*)[72])(smemraw + 256 * 72 * 2);  // [64][72]
  const int t = threadIdx.x;
  const int mhalf = bid & 1, nblk = bid >> 1;
  const int m0 = mhalf * 256, n0 = nblk * 64;
  const int lane = t & 63, wv = t >> 6;

#pragma unroll 4
  for (int rr = 0; rr < 64; ++rr) {
    const int row = m0 + wv * 64 + rr;
    const size_t idx = (size_t)row * LL + lane;
    float s = sp[idx] + sp[idx + (size_t)BB * LL] + sp[idx + (size_t)2 * BB * LL] +
              sp[idx + (size_t)3 * BB * LL] + attn_b[lane];
    float m = s;
#pragma unroll
    for (int off = 32; off; off >>= 1) m = fmaxf(m, __shfl_xor(m, off));
    float e = __expf(s - m);
    float sum = e;
#pragma unroll
    for (int off = 32; off; off >>= 1) sum += __shfl_xor(sum, off);
    float wvv = e / sum;
    if (nblk == 0) attn_out[idx] = wvv;
    aw[wv * 64 + rr][lane] = f2bf(wvv);
  }
  {
    const int n = t & 63, kb4 = (t >> 6) * 16;
#pragma unroll
    for (int kk = 0; kk < 16; ++kk)
      Bs[n][kb4 + kk] = f2bf(enc[(size_t)(kb4 + kk) * HH + n0 + n]);
  }
  __syncthreads();
  const int lg = lane >> 4, lr = lane & 15;
  f32x4 acc[4][4] = {};
#pragma unroll
  for (int kk = 0; kk < 2; ++kk) {
    bf16x8 a[4], b[4];
#pragma unroll
    for (int i = 0; i < 4; ++i)
      a[i] = *(const bf16x8*)(&aw[wv * 64 + 16 * i + lr][kk * 32 + lg * 8]);
#pragma unroll
    for (int j = 0; j < 4; ++j)
      b[j] = *(const bf16x8*)(&Bs[16 * j + lr][kk * 32 + lg * 8]);
#pragma unroll
    for (int i = 0; i < 4; ++i)
#pragma unroll
      for (int j = 0; j < 4; ++j)
        acc[i][j] = __builtin_amdgcn_mfma_f32_16x16x32_bf16(a[i], b[j], acc[i][j], 0, 0, 0);
  }
#pragma unroll
  for (int i = 0; i < 4; ++i)
#pragma unroll
    for (int j = 0; j < 4; ++j)
#pragma unroll
      for (int rr = 0; rr < 4; ++rr) {
        const int row = m0 + wv * 64 + 16 * i + lg * 4 + rr;
        A_cat[(size_t)row * 2048 + 1024 + n0 + 16 * j + lr] = f2bf(acc[i][j][rr]);
      }
}

static __device__ void dev_convert(int bid, const float* __restrict__ emb,
                                   const float* __restrict__ h0, bf16* __restrict__ A_cat,
                                   bf16* __restrict__ cat2) {
  int i = bid * 256 + threadIdx.x;
  int b = i >> 10, h = i & 1023;
  bf16 e = f2bf(emb[i]);
  A_cat[(size_t)b * 2048 + h] = e;
  cat2[(size_t)b * 2048 + h] = e;
  cat2[(size_t)b * 2048 + 1024 + h] = f2bf(h0[i]);
}

static __device__ void dev_smax(int bid, const float* __restrict__ sp,
                                const float* __restrict__ attn_b, float* __restrict__ attn_out,
                                bf16* __restrict__ aw_b) {
  const int t = threadIdx.x;
  const int row = bid * 4 + (t >> 6);
  const int l = t & 63;
  const size_t idx = (size_t)row * LL + l;
  float s = sp[idx] + sp[idx + (size_t)BB * LL] + sp[idx + (size_t)2 * BB * LL] +
            sp[idx + (size_t)3 * BB * LL] + attn_b[l];
  float m = s;
#pragma unroll
  for (int off = 32; off; off >>= 1) m = fmaxf(m, __shfl_xor(m, off));
  float e = __expf(s - m);
  float sum = e;
#pragma unroll
  for (int off = 32; off; off >>= 1) sum += __shfl_xor(sum, off);
  float wv = e / sum;
  attn_out[idx] = wv;
  aw_b[idx] = f2bf(wv);
}

// gru from split-K partials: h1 from gi parts (4) + b_ih, gh parts (4) + b_hh
static __device__ void dev_gru4(int bid, const float* __restrict__ gip,
                                const float* __restrict__ ghp, const float* __restrict__ b_ih,
                                const float* __restrict__ b_hh, const float* __restrict__ h0,
                                float* __restrict__ h1_out, bf16* __restrict__ h1b) {
  int i = bid * 256 + threadIdx.x;
  int b = i >> 10, h = i & 1023;
  size_t base = (size_t)b * 3072;
  const size_t PS = (size_t)BB * 3072;
  float ir = b_ih[h], iz = b_ih[1024 + h], in_ = b_ih[2048 + h];
  float hr = b_hh[h], hz = b_hh[1024 + h], hn = b_hh[2048 + h];
#pragma unroll
  for (int p = 0; p < 4; ++p) {
    ir += gip[p * PS + base + h];
    iz += gip[p * PS + base + 1024 + h];
    in_ += gip[p * PS + base + 2048 + h];
    hr += ghp[p * PS + base + h];
    hz += ghp[p * PS + base + 1024 + h];
    hn += ghp[p * PS + base + 2048 + h];
  }
  float r = 1.f / (1.f + __expf(-(ir + hr)));
  float z = 1.f / (1.f + __expf(-(iz + hz)));
  float n = tanhf(in_ + r * hn);
  float h1 = (1.f - z) * n + z * h0[i];
  h1_out[i] = h1;
  h1b[i] = f2bf(h1);
}

static __device__ void dev_gru(int bid, const float* __restrict__ gi, const float* __restrict__ gh,
                               const float* __restrict__ h0, float* __restrict__ h1_out,
                               bf16* __restrict__ h1b) {
  int i = bid * 256 + threadIdx.x;
  int b = i >> 10, h = i & 1023;
  size_t base = (size_t)b * 3072;
  float ir = gi[base + h], iz = gi[base + 1024 + h], in_ = gi[base + 2048 + h];
  float hr = gh[base + h], hz = gh[base + 1024 + h], hn = gh[base + 2048 + h];
  float r = 1.f / (1.f + __expf(-(ir + hr)));
  float z = 1.f / (1.f + __expf(-(iz + hz)));
  float n = tanhf(in_ + r * hn);
  float h1 = (1.f - z) * n + z * h0[i];
  h1_out[i] = h1;
  h1b[i] = f2bf(h1);
}

// x = relu(sum comb partials + comb_b) -> bf16
static __device__ void dev_xred(int bid, const float* __restrict__ cp,
                                const float* __restrict__ comb_b, bf16* __restrict__ x) {
  int i = bid * 256 + threadIdx.x;  // < 512*1024
  int col = i & 1023;
  const size_t PS = (size_t)BB * HH;
  float s = cp[i] + cp[PS + i] + cp[2 * PS + i] + cp[3 * PS + i] + comb_b[col];
  x[i] = f2bf(fmaxf(s, 0.f));
}

// ================= fast-path launches =================

// L1: fp32 scores (512) + convert (2048) + tr slice (2600)
__global__ __launch_bounds__(256) void k_head(const float* __restrict__ emb,
                                              const float* __restrict__ h0,
                                              const float* __restrict__ attn_W,
                                              float* __restrict__ sp, bf16* __restrict__ A_cat,
                                              bf16* __restrict__ cat2,
                                              const float* __restrict__ W, bf16* __restrict__ Wt,
                                              int trOff) {
  __shared__ __align__(16) char sm[16640];
  const int bid = blockIdx.x;
  if (bid < 512) {
    const int wv = threadIdx.x >> 6, lane = threadIdx.x & 63;
    const int rq = bid & 127, kc = bid >> 7;
    const int row = rq * 4 + wv;
    const float* Ar = (kc < 2) ? (emb + (size_t)row * HH + kc * 512)
                               : (h0 + (size_t)row * HH + (kc - 2) * 512);
    const float* Wb = attn_W + (size_t)(kc * 512) * LL + lane;
    float acc = 0.f;
#pragma unroll 4
    for (int k8 = 0; k8 < 64; ++k8) {
      float4 a0 = *(const float4*)(Ar + k8 * 8);
      float4 a1 = *(const float4*)(Ar + k8 * 8 + 4);
      const float* wp = Wb + (size_t)k8 * 8 * LL;
      acc = fmaf(a0.x, wp[0], acc);
      acc = fmaf(a0.y, wp[LL], acc);
      acc = fmaf(a0.z, wp[2 * LL], acc);
      acc = fmaf(a0.w, wp[3 * LL], acc);
      acc = fmaf(a1.x, wp[4 * LL], acc);
      acc = fmaf(a1.y, wp[5 * LL], acc);
      acc = fmaf(a1.z, wp[6 * LL], acc);
      acc = fmaf(a1.w, wp[7 * LL], acc);
    }
    sp[((size_t)kc * BB + row) * LL + lane] = acc;
  } else if (bid < 2560) {
    dev_convert(bid - 512, emb, h0, A_cat, cat2);
  } else {
    int tb = trOff + bid - 2560;
    if (tb < TRB) dev_tr(sm, tb, W, Wt);
  }
}

// L2: sapp (32) + gh split-K=4 (384) + tr slice (800)
__global__ __launch_bounds__(256) void k_sapp_gh(const float* sp, const float* attn_b,
                                                 float* attn_out, const float* enc, bf16* A_cat,
                                                 const bf16* cat2, const float* W_hh,
                                                 float* ghp, const float* W, bf16* Wt,
                                                 int trOff) {
  __shared__ __align__(16) char sm[46080];
  const int bid = blockIdx.x;
  if (bid < 32) dev_sapp(sm, bid, sp, attn_b, attn_out, enc, A_cat);
  else if (bid < 416)
    dev_gemm<1, 0>(sm, bid - 32, 96, cat2 + 1024, W_hh, nullptr, ghp, 3 * HH, 256, 3 * HH,
                   2048, HH);
  else {
    int tb = trOff + bid - 416;
    if (tb < TRB) dev_tr(sm, tb, W, Wt);
  }
}

// L3: comb split-K=4 (128) + tr
__global__ __launch_bounds__(256, 3) void k_fat_comb4(const bf16* A_cat, const float* comb_W,
                                                      float* combp, const float* W, bf16* Wt,
                                                      int trOff) {
  __shared__ __align__(16) char sm[16640];
  const int bid = blockIdx.x;
  if (bid < 128)
    dev_gemm<0, 0>(sm, bid, 32, A_cat, comb_W, nullptr, combp, HH, 512, HH, 2048, 0);
  else { int tb = trOff + bid - 128; if (tb < TRB) dev_tr(sm, tb, W, Wt); }
}

// L4: x reduce (2048) + tr
__global__ __launch_bounds__(256) void k_fat_xred(const float* combp, const float* comb_b,
                                                  bf16* x, const float* W, bf16* Wt, int trOff) {
  __shared__ __align__(16) char sm[16640];
  const int bid = blockIdx.x;
  if (bid < 2048) dev_xred(bid, combp, comb_b, x);
  else { int tb = trOff + bid - 2048; if (tb < TRB) dev_tr(sm, tb, W, Wt); }
}

// L5: gi split-K=4 (384) + tr
__global__ __launch_bounds__(256, 3) void k_fat_gi4(const bf16* x, const float* W_ih, float* gip,
                                                    const float* W, bf16* Wt, int trOff) {
  __shared__ __align__(16) char sm[16640];
  const int bid = blockIdx.x;
  if (bid < 384)
    dev_gemm<1, 0>(sm, bid, 96, x, W_ih, nullptr, gip, 3 * HH, 256, 3 * HH, HH, HH);
  else { int tb = trOff + bid - 384; if (tb < TRB) dev_tr(sm, tb, W, Wt); }
}

// L6: gru from partials (2048) + tr
__global__ __launch_bounds__(256) void k_fat_gru4(const float* gip, const float* ghp,
                                                  const float* b_ih, const float* b_hh,
                                                  const float* h0, float* h1_out, bf16* h1b,
                                                  const float* W, bf16* Wt, int trOff) {
  __shared__ __align__(16) char sm[16640];
  const int bid = blockIdx.x;
  if (bid < 2048) dev_gru4(bid, gip, ghp, b_ih, b_hh, h0, h1_out, h1b);
  else { int tb = trOff + bid - 2048; if (tb < TRB) dev_tr(sm, tb, W, Wt); }
}

// ===== big GEMM (R11-verified): 256x128 tile, 8 waves, NBUF=2, 2 blocks/CU =====
__global__ __launch_bounds__(512, 4) void k_gemm_big(const bf16* __restrict__ A,
                                                     const bf16* __restrict__ Bt,
                                                     const float* __restrict__ bias,
                                                     bf16* __restrict__ C,
                                                     float* __restrict__ pm,
                                                     float* __restrict__ ps) {
  __shared__ __align__(16) bf16 Asm[2][8192];
  __shared__ __align__(16) bf16 Bsm[2][4096];
  __shared__ float sm_m[2][256], sm_s[2][256];
  const int t = threadIdx.x;
  const int bid = blockIdx.x;
  const int nwg = gridDim.x;  // 788
  const int xcd = bid & 7, jj = bid >> 3;
  const int q = nwg >> 3, r = nwg & 7;
  const int w = (xcd < r ? xcd * (q + 1) : r * (q + 1) + (xcd - r) * q) + jj;
  const int m0 = (w & 1) * 256;
  const int n0 = (w >> 1) * 128;
  const int lane = t & 63, wv = t >> 6;
  const int wvm = wv >> 1, wvn = wv & 1;
  const int lg = lane >> 4, lr = lane & 15;

  const int srow = lane >> 2;
  const int skk = (((lane & 3) ^ ((lane >> 3) & 3))) * 8;
  const bf16* Aa0 = A + (size_t)(m0 + wv * 32 + srow) * HH + skk;
  const bf16* Aa1 = Aa0 + (size_t)16 * HH;
  const bf16* Bb0 = Bt + (size_t)(n0 + wv * 16 + srow) * HH + skk;

  auto stage = [&](int buf, int koff) {
    __builtin_amdgcn_global_load_lds((g_u32*)(Aa0 + koff), (l_u32*)(&Asm[buf][wv * 1024]), 16, 0, 0);
    __builtin_amdgcn_global_load_lds((g_u32*)(Aa1 + koff), (l_u32*)(&Asm[buf][wv * 1024 + 512]), 16, 0, 0);
    __builtin_amdgcn_global_load_lds((g_u32*)(Bb0 + koff), (l_u32*)(&Bsm[buf][wv * 512]), 16, 0, 0);
  };

  f32x4 acc[4][4] = {};
  stage(0, 0);
  __syncthreads();
  int cur = 0;
  const int nk = HH / 32;
  const int rga = (lr >> 1) & 3;
  for (int ik = 0; ik < nk; ++ik) {
    if (ik + 1 < nk) stage(cur ^ 1, (ik + 1) * 32);
    bf16x8 a[4], b[4];
#pragma unroll
    for (int i = 0; i < 4; ++i)
      a[i] = *(const bf16x8*)(&Asm[cur][(wvm * 64 + 16 * i + lr) * 32 + ((lg ^ rga) * 8)]);
#pragma unroll
    for (int j = 0; j < 4; ++j)
      b[j] = *(const bf16x8*)(&Bsm[cur][(wvn * 64 + 16 * j + lr) * 32 + ((lg ^ rga) * 8)]);
#pragma unroll
    for (int i = 0; i < 4; ++i)
#pragma unroll
      for (int j = 0; j < 4; ++j)
        acc[i][j] = __builtin_amdgcn_mfma_f32_16x16x32_bf16(a[i], b[j], acc[i][j], 0, 0, 0);
    __syncthreads();
    cur ^= 1;
  }

  float bb[4];
#pragma unroll
  for (int j = 0; j < 4; ++j) {
    const int col = n0 + wvn * 64 + 16 * j + lr;
    bb[j] = (col < VV) ? bias[col] : 0.f;
  }
#pragma unroll
  for (int i = 0; i < 4; ++i)
#pragma unroll
    for (int j = 0; j < 4; ++j)
#pragma unroll
      for (int rr = 0; rr < 4; ++rr) acc[i][j][rr] += bb[j];

#pragma unroll
  for (int i = 0; i < 4; ++i)
#pragma unroll
    for (int j = 0; j < 4; ++j) {
      const int col = n0 + wvn * 64 + 16 * j + lr;
      if (col < VV) {
#pragma unroll
        for (int rr = 0; rr < 4; ++rr) {
          const int row = m0 + wvm * 64 + 16 * i + lg * 4 + rr;
          C[(size_t)row * ZS + col] = f2bf(acc[i][j][rr]);
        }
      }
    }

#pragma unroll
  for (int i = 0; i < 4; ++i)
#pragma unroll
    for (int rr = 0; rr < 4; ++rr) {
      float mr = -1e30f;
#pragma unroll
      for (int j = 0; j < 4; ++j)
        if (n0 + wvn * 64 + 16 * j + lr < VV) mr = fmaxf(mr, acc[i][j][rr]);
      float sr = 0.f;
#pragma unroll
      for (int j = 0; j < 4; ++j)
        if (n0 + wvn * 64 + 16 * j + lr < VV) sr += __expf(acc[i][j][rr] - mr);
#pragma unroll
      for (int off = 1; off < 16; off <<= 1) {
        float mo = __shfl_xor(mr, off), so = __shfl_xor(sr, off);
        float nm = fmaxf(mr, mo);
        sr = sr * __expf(mr - nm) + so * __expf(mo - nm);
        mr = nm;
      }
      if (lr == 0) {
        const int row = wvm * 64 + 16 * i + lg * 4 + rr;
        sm_m[wvn][row] = mr;
        sm_s[wvn][row] = sr;
      }
    }
  __syncthreads();
  if (t < 256) {
    float M = sm_m[0][t], S = sm_s[0][t];
    float mo = sm_m[1][t], so = sm_s[1][t];
    float nm = fmaxf(M, mo);
    S = S * __expf(M - nm) + so * __expf(mo - nm);
    M = nm;
    const int grow = m0 + t;
    pm[(size_t)grow * PLD + (w >> 1)] = M;
    ps[(size_t)grow * PLD + (w >> 1)] = S;
  }
}

// ================= final subtract with fused per-row lse =================
__global__ __launch_bounds__(256) void k_out(const bf16* __restrict__ z,
                                             const float* __restrict__ pm,
                                             const float* __restrict__ ps,
                                             float* __restrict__ out) {
  const int b = blockIdx.y;
  const int t = threadIdx.x;
  __shared__ float lsev;
  if (t < 64) {
    float m = -1e30f, s = 0.f;
    for (int tt = t; tt < NT; tt += 64) {
      float mo = pm[(size_t)b * PLD + tt], so = ps[(size_t)b * PLD + tt];
      float nm = fmaxf(m, mo);
      s = s * __expf(m - nm) + so * __expf(mo - nm);
      m = nm;
    }
#pragma unroll
    for (int off = 32; off; off >>= 1) {
      float mo = __shfl_xor(m, off), so = __shfl_xor(s, off);
      float nm = fmaxf(m, mo);
      s = s * __expf(m - nm) + so * __expf(mo - nm);
      m = nm;
    }
    if (t == 0) lsev = logf(s) + m;
  }
  __syncthreads();
  const float l = lsev;
  const int c = (blockIdx.x * 256 + t) * 4;
  if (c >= VV) return;
  const bf16* zr = z + (size_t)b * ZS;
  float* orow = out + (size_t)b * VV;
  if (c + 4 <= VV) {
    bf16x4v v = *(const bf16x4v*)(zr + c);
    float4 o = make_float4((float)v[0] - l, (float)v[1] - l, (float)v[2] - l, (float)v[3] - l);
    *(float4*)(orow + c) = o;
  } else {
    for (int e = c; e < VV; ++e) orow[e] = (float)zr[e] - l;
  }
}

// ================= fallback (small ws): standalone kernels =================

template <int BLAYOUT, int OMODE>
__global__ __launch_bounds__(256, 3) void k_gemm(const bf16* A, const float* Bm, const float* bias,
                                                 void* Cout, int N, int K, int ldc, int lda,
                                                 int ldb) {
  __shared__ __align__(16) char sm[10240];
  dev_gemm<BLAYOUT, OMODE>(sm, blockIdx.y * gridDim.x + blockIdx.x, gridDim.x, A, Bm, bias, Cout,
                           N, K, ldc, lda, ldb);
}

__global__ __launch_bounds__(512) void k_lsm(const bf16* __restrict__ z, float* __restrict__ out) {
  const int b = blockIdx.x, t = threadIdx.x;
  const bf16* zr = z + (size_t)b * ZS;
  float m = -1e30f, s = 0.f;
  for (int c = t; c < 6282; c += 512) {
    bf16x8 v = *(const bf16x8*)(zr + (size_t)c * 8);
#pragma unroll
    for (int e = 0; e < 8; ++e) {
      float x = (float)v[e];
      float nm = fmaxf(m, x);
      s = s * __expf(m - nm) + __expf(x - nm);
      m = nm;
    }
  }
  if (t == 0) {
    float x = (float)zr[VV - 1];
    float nm = fmaxf(m, x);
    s = s * __expf(m - nm) + __expf(x - nm);
    m = nm;
  }
  for (int off = 32; off; off >>= 1) {
    float mo = __shfl_xor(m, off), so = __shfl_xor(s, off);
    float nm = fmaxf(m, mo);
    s = s * __expf(m - nm) + so * __expf(mo - nm);
    m = nm;
  }
  __shared__ float ms[8], ss[8];
  if ((t & 63) == 0) { ms[t >> 6] = m; ss[t >> 6] = s; }
  __syncthreads();
  if (t == 0) {
    float M = ms[0], S = ss[0];
    for (int wv = 1; wv < 8; ++wv) {
      float nm = fmaxf(M, ms[wv]);
      S = S * __expf(M - nm) + ss[wv] * __expf(ms[wv] - nm);
      M = nm;
    }
    ss[0] = logf(S) + M;
  }
  __syncthreads();
  const float lse = ss[0];
  float* orow = out + (size_t)b * VV;
  for (int v = t; v < VV; v += 512) orow[v] = (float)zr[v] - lse;
}

__global__ void k_convertG(const float* emb, const float* h0, bf16* A_cat, bf16* cat2) {
  dev_convert(blockIdx.x, emb, h0, A_cat, cat2);
}
__global__ void k_smaxG(const float* sp, const float* attn_b, float* attn_out, bf16* aw_b) {
  dev_smax(blockIdx.x, sp, attn_b, attn_out, aw_b);
}
__global__ void k_gruG(const float* gi, const float* gh, const float* h0, float* h1_out,
                       bf16* h1b) {
  dev_gru(blockIdx.x, gi, gh, h0, h1_out, h1b);
}

// ================= host =================

extern "C" void kernel_launch(void* const* d_in, const int* in_sizes, int n_in,
                              void* d_out, int out_size, void* d_ws, size_t ws_size,
                              hipStream_t stream) {
  const float* emb    = (const float*)d_in[0];
  const float* h0     = (const float*)d_in[1];
  const float* enc    = (const float*)d_in[2];
  const float* attn_W = (const float*)d_in[3];
  const float* attn_b = (const float*)d_in[4];
  const float* comb_W = (const float*)d_in[5];
  const float* comb_b = (const float*)d_in[6];
  const float* W_ih   = (const float*)d_in[7];
  const float* W_hh   = (const float*)d_in[8];
  const float* b_ih   = (const float*)d_in[9];
  const float* b_hh   = (const float*)d_in[10];
  const float* out_W  = (const float*)d_in[11];
  const float* out_b  = (const float*)d_in[12];

  float* out      = (float*)d_out;
  float* h1out    = out + (size_t)BB * VV;
  float* attn_out = h1out + (size_t)BB * HH;

  char* ws = (char*)d_ws;
  bf16* A_cat  = (bf16*)(ws);
  bf16* cat2   = (bf16*)(ws + 2097152);
  bf16* x      = (bf16*)(ws + 4194304);
  bf16* h1b    = (bf16*)(ws + 5242880);
  float* gi    = (float*)(ws + 6291456);             // fallback only
  float* gh    = (float*)(ws + 12582912);            // fallback only
  float* sp    = (float*)(ws + 18874368);
  bf16* aw_b   = (bf16*)(ws + 19398656);
  bf16* z      = (bf16*)(ws + 19464192);             // 512 x ZS bf16 (51.5 MB)
  bf16* Wt     = (bf16*)(ws + 70934528);             // 50432 x 1024 bf16 (103.3 MB)
  float* pm    = (float*)(ws + 174219264);           // 512 x 400 f32
  float* ps    = (float*)(ws + 175038464);           // 512 x 400 f32
  float* combp = (float*)(ws + 175857664);           // 4 x 512 x 1024 f32 (8.4 MB)
  float* ghp   = (float*)(ws + 184246272);           // 4 x 512 x 3072 f32 (25.2 MB)
  float* gip   = (float*)(ws + 209412096);           // 4 x 512 x 3072 f32 (25.2 MB)
  const size_t WS_NEED = 234577920ull;

  if (ws_size >= WS_NEED) {
    // tr slices: L1 2600, L2 800, L3 2400, L4 2200, L5 2400, L6 2208  (sum = 12608 = TRB)
    int off = 0;
    k_head<<<2560 + 2600, 256, 0, stream>>>(emb, h0, attn_W, sp, A_cat, cat2, out_W, Wt, off);
    off += 2600;
    k_sapp_gh<<<416 + 800, 256, 0, stream>>>(sp, attn_b, attn_out, enc, A_cat, cat2, W_hh, ghp,
                                             out_W, Wt, off);
    off += 800;
    k_fat_comb4<<<128 + 2400, 256, 0, stream>>>(A_cat, comb_W, combp, out_W, Wt, off); off += 2400;
    k_fat_xred<<<2048 + 2200, 256, 0, stream>>>(combp, comb_b, x, out_W, Wt, off); off += 2200;
    k_fat_gi4<<<384 + 2400, 256, 0, stream>>>(x, W_ih, gip, out_W, Wt, off); off += 2400;
    k_fat_gru4<<<2048 + (TRB - off), 256, 0, stream>>>(gip, ghp, b_ih, b_hh, h0, h1out, h1b,
                                                       out_W, Wt, off);
    k_gemm_big<<<2 * NT, 512, 0, stream>>>(h1b, Wt, out_b, z, pm, ps);
    k_out<<<dim3(50, BB), 256, 0, stream>>>(z, pm, ps, out);
  } else {
    k_convertG<<<BB * HH / 256, 256, 0, stream>>>(emb, h0, A_cat, cat2);
    k_gemm<0, 0><<<dim3(2, 4), 256, 0, stream>>>(cat2, attn_W, nullptr, sp, LL, 512, LL, 2048, 0);
    k_smaxG<<<BB / 4, 256, 0, stream>>>(sp, attn_b, attn_out, aw_b);
    k_gemm<0, 2><<<dim3(32, 1), 256, 0, stream>>>(aw_b, enc, nullptr, A_cat + 1024, HH, LL, 2048, LL, 0);
    k_gemm<0, 1><<<dim3(32, 1), 256, 0, stream>>>(A_cat, comb_W, comb_b, x, HH, 2 * HH, HH, 2 * HH, 0);
    k_gemm<1, 0><<<dim3(96, 1), 256, 0, stream>>>(x, W_ih, b_ih, gi, 3 * HH, HH, 3 * HH, HH, HH);
    k_gemm<1, 0><<<dim3(96, 1), 256, 0, stream>>>(cat2 + 1024, W_hh, b_hh, gh, 3 * HH, HH, 3 * HH, 2048, HH);
    k_gruG<<<BB * HH / 256, 256, 0, stream>>>(gi, gh, h0, h1out, h1b);
    k_gemm<0, 2><<<dim3(2 * ((VV + 63) / 64), 1), 256, 0, stream>>>(h1b, out_W, out_b, z, VV, HH, ZS, HH, 0);
    k_lsm<<<BB, 512, 0, stream>>>(z, out);
  }
}